// Round 8
// baseline (6343.562 us; speedup 1.0000x reference)
//
#include <hip/hip_runtime.h>

#define N_NODESC 20000
#define N_EDGESC 640000

typedef _Float16 f16;
typedef __attribute__((ext_vector_type(4))) _Float16 f16x4;
typedef __attribute__((ext_vector_type(8))) _Float16 f16x8;
typedef __attribute__((ext_vector_type(4))) float f32x4;

__device__ __forceinline__ f32x4 mfma16(f16x8 a, f16x8 b, f32x4 c){
  return __builtin_amdgcn_mfma_f32_16x16x32_f16(a, b, c, 0, 0, 0);
}
__device__ __forceinline__ float sigm(float x){ return 1.f/(1.f+__expf(-x)); }
__device__ __forceinline__ float tanh_(float x){
  x = fminf(fmaxf(x, -15.f), 15.f);
  float e = __expf(-2.f*x);
  return (1.f - e)/(1.f + e);
}
__device__ __forceinline__ void stage16(const void* g, void* l){
  __builtin_amdgcn_global_load_lds((const __attribute__((address_space(1))) unsigned int*)g,
                                   (__attribute__((address_space(3))) unsigned int*)l, 16, 0, 0);
}
#define SB       __builtin_amdgcn_sched_barrier(0)
#define AS_VM(n) do{ asm volatile("s_waitcnt vmcnt(" #n ")" ::: "memory"); SB; }while(0)
#define AS_LG    do{ asm volatile("s_waitcnt lgkmcnt(0)" ::: "memory"); SB; }while(0)
#define BAR      do{ __builtin_amdgcn_s_barrier(); SB; }while(0)

// ---------------- CSR construction ----------------
__global__ __launch_bounds__(256) void k_hist(const int* __restrict__ dst, int* __restrict__ cnt){
  int e = blockIdx.x*256 + threadIdx.x;
  if(e < N_EDGESC) atomicAdd(&cnt[dst[e]], 1);
}

__global__ __launch_bounds__(1024) void k_scan(const int* __restrict__ cnt, int* __restrict__ row_ptr,
    float* __restrict__ deg_inv, float* __restrict__ deg_is){
  __shared__ int wsum[16];
  int t = threadIdx.x;
  int base = t*20;
  int loc[20]; int s = 0;
  #pragma unroll
  for(int i=0;i<20;i++){ int idx=base+i; int v = (idx<N_NODESC)? cnt[idx] : 0; loc[i]=s; s+=v; }
  int lane = t&63, wv = t>>6;
  int incl = s;
  #pragma unroll
  for(int off=1; off<64; off<<=1){ int u = __shfl_up(incl, off); if(lane>=off) incl += u; }
  if(lane==63) wsum[wv]=incl;
  __syncthreads();
  int woff=0;
  for(int i=0;i<wv;i++) woff += wsum[i];
  int excl = woff + incl - s;
  #pragma unroll
  for(int i=0;i<20;i++){
    int idx=base+i;
    if(idx<N_NODESC){
      row_ptr[idx] = excl + loc[i];
      float d = (float)(cnt[idx]+1);
      deg_inv[idx] = 1.f/d;
      deg_is[idx]  = rsqrtf(d);
    }
  }
  if(t==1023) row_ptr[N_NODESC] = woff + incl;
}

__global__ __launch_bounds__(256) void k_fill(const int* __restrict__ src, const int* __restrict__ dst,
    const int* __restrict__ row_ptr, int* __restrict__ cursor, const float* __restrict__ deg_is,
    int* __restrict__ colv, float* __restrict__ normv){
  int e = blockIdx.x*256 + threadIdx.x;
  if(e >= N_EDGESC) return;
  int d = dst[e], s = src[e];
  int p = atomicAdd(&cursor[d], 1);
  int idx = row_ptr[d] + p;
  colv[idx] = s;
  normv[idx] = deg_is[s]*deg_is[d];
}

// ---------------- weight packing (f16, MFMA B-fragment order) ----------------
__global__ __launch_bounds__(256) void k_pack(const float* __restrict__ w, f16* __restrict__ dstp,
    int K, int NO, int trans){
  int t = blockIdx.x*256 + threadIdx.x;
  if(t >= K*NO) return;
  int i = t&7, g = (t>>3)&3, rest = t>>5;
  int c = rest % NO, kb = rest / NO;
  int k = kb*32 + g*8 + i;
  float v = trans ? w[(size_t)c*K + k] : w[(size_t)k*NO + c];
  dstp[t] = (f16)v;
}

// ---------------- aggregation ----------------
__global__ __launch_bounds__(256) void k_agg64(const float* __restrict__ x,
    const int* __restrict__ row_ptr, const int* __restrict__ colv,
    const float* __restrict__ normv, const float* __restrict__ deg_inv,
    f16* __restrict__ Ohi, f16* __restrict__ Olo){
  int n = (blockIdx.x*256 + threadIdx.x)>>6;
  int c = threadIdx.x&63;
  if(n >= N_NODESC) return;
  float acc = deg_inv[n]*x[(size_t)n*64 + c];
  int e0 = row_ptr[n], e1 = row_ptr[n+1];
  int e = e0;
  for(; e+4<=e1; e+=4){
    int s0=colv[e],s1=colv[e+1],s2=colv[e+2],s3=colv[e+3];
    float w0=normv[e],w1=normv[e+1],w2=normv[e+2],w3=normv[e+3];
    float v0=x[(size_t)s0*64+c], v1=x[(size_t)s1*64+c];
    float v2=x[(size_t)s2*64+c], v3=x[(size_t)s3*64+c];
    acc += w0*v0 + w1*v1 + w2*v2 + w3*v3;
  }
  for(; e<e1; e++) acc += normv[e]*x[(size_t)colv[e]*64+c];
  f16 hi = (f16)acc;
  f16 lo = (f16)(acc - (float)hi);
  Ohi[(size_t)n*64+c]=hi; Olo[(size_t)n*64+c]=lo;
}

__global__ __launch_bounds__(256) void k_agg256(const f16* __restrict__ x1,
    const int* __restrict__ row_ptr, const int* __restrict__ colv,
    const float* __restrict__ normv, const float* __restrict__ deg_inv,
    f16* __restrict__ Ohi, f16* __restrict__ Olo){
  int n = (blockIdx.x*256 + threadIdx.x)>>6;
  int lane = threadIdx.x&63;
  if(n >= N_NODESC) return;
  const f16x4* xv = (const f16x4*)x1;
  f32x4 acc = __builtin_convertvector(xv[(size_t)n*64 + lane], f32x4) * deg_inv[n];
  int e0 = row_ptr[n], e1 = row_ptr[n+1];
  int e = e0;
  for(; e+4<=e1; e+=4){
    int s0=colv[e],s1=colv[e+1],s2=colv[e+2],s3=colv[e+3];
    float w0=normv[e],w1=normv[e+1],w2=normv[e+2],w3=normv[e+3];
    f32x4 v0=__builtin_convertvector(xv[(size_t)s0*64+lane], f32x4);
    f32x4 v1=__builtin_convertvector(xv[(size_t)s1*64+lane], f32x4);
    f32x4 v2=__builtin_convertvector(xv[(size_t)s2*64+lane], f32x4);
    f32x4 v3=__builtin_convertvector(xv[(size_t)s3*64+lane], f32x4);
    acc += v0*w0; acc += v1*w1; acc += v2*w2; acc += v3*w3;
  }
  for(; e<e1; e++) acc += __builtin_convertvector(xv[(size_t)colv[e]*64+lane], f32x4)*normv[e];
  f16x4 hi = __builtin_convertvector(acc, f16x4);
  f32x4 hf = __builtin_convertvector(hi, f32x4);
  f16x4 lo = __builtin_convertvector(acc - hf, f16x4);
  ((f16x4*)Ohi)[(size_t)n*64+lane] = hi;
  ((f16x4*)Olo)[(size_t)n*64+lane] = lo;
}

// ---------------- GCN1: K=64, N=256, single-stage LDS [p][kb][q][row][16B] ----------------
__global__ __launch_bounds__(256) void k_gcn1(const f16* __restrict__ Ahi, const f16* __restrict__ Alo,
    const f16* __restrict__ Bp, const float* __restrict__ bias, f16* __restrict__ C){
  __shared__ f16x8 ldsv[1024];                 // 16KB
  char* lds = (char*)ldsv;
  const int tid = threadIdx.x, lane = tid&63, w = tid>>6, l15 = lane&15, q = lane>>4;
  const int m0 = blockIdx.x*64;
  int rg = m0 + lane; if(rg > N_NODESC-1) rg = N_NODESC-1;
  const f16* pl[2] = {Ahi, Alo};
  #pragma unroll
  for(int i=0;i<4;i++){
    int region = i*4 + w;
    int p = region>>3, kbb = (region>>2)&1, qq = region&3;
    stage16((const char*)pl[p] + (size_t)rg*128 + kbb*64 + qq*16, lds + region*1024);
  }
  AS_VM(0);
  BAR;
  f32x4 acc[4][4];
  #pragma unroll
  for(int rt=0;rt<4;rt++)
    #pragma unroll
    for(int ct=0;ct<4;ct++) acc[rt][ct] = (f32x4){0.f,0.f,0.f,0.f};
  #pragma unroll
  for(int kb=0;kb<2;kb++){
    f16x8 bf[4];
    #pragma unroll
    for(int ct=0;ct<4;ct++){
      int c = w*64 + ct*16 + l15;
      bf[ct] = *(const f16x8*)(Bp + ((unsigned)(kb*256 + c)*4 + q)*8);
    }
    #pragma unroll
    for(int rt=0;rt<4;rt++){
      f16x8 ah = *(const f16x8*)(lds + ((0*2+kb)*4)*1024 + q*1024 + (rt*16+l15)*16);
      f16x8 al = *(const f16x8*)(lds + ((1*2+kb)*4)*1024 + q*1024 + (rt*16+l15)*16);
      #pragma unroll
      for(int ct=0;ct<4;ct++){
        acc[rt][ct] = mfma16(ah, bf[ct], acc[rt][ct]);
        acc[rt][ct] = mfma16(al, bf[ct], acc[rt][ct]);
      }
    }
  }
  #pragma unroll
  for(int rt=0;rt<4;rt++)
    #pragma unroll
    for(int ct=0;ct<4;ct++){
      int c = w*64 + ct*16 + l15;
      float bv = bias[c];
      #pragma unroll
      for(int j=0;j<4;j++){
        int r = m0 + rt*16 + q*4 + j;
        if(r < N_NODESC) C[(size_t)r*256 + c] = (f16)fmaxf(acc[rt][ct][j] + bv, 0.f);
      }
    }
}

// ---------------- GCN2: K=256 (2 planes), pipelined, triple-buffer LDS ----------------
__global__ __launch_bounds__(256,2) void k_gcn2(const f16* __restrict__ Ahi, const f16* __restrict__ Alo,
    const f16* __restrict__ Bp, const float* __restrict__ bias,
    f16* __restrict__ Chi, f16* __restrict__ Clo){
  __shared__ f16x8 ldsv[1536];                 // 3 bufs x 8KB
  char* lds = (char*)ldsv;
  const int tid = threadIdx.x, lane = tid&63, w = tid>>6, l15 = lane&15, q = lane>>4;
  const int m0 = blockIdx.x*64;
  int rg = m0 + lane; if(rg > N_NODESC-1) rg = N_NODESC-1;
  const size_t abyte = (size_t)rg*512;
  const f16* pl[2] = {Ahi, Alo};
  f32x4 acc[4][4];
  #pragma unroll
  for(int rt=0;rt<4;rt++)
    #pragma unroll
    for(int ct=0;ct<4;ct++) acc[rt][ct] = (f32x4){0.f,0.f,0.f,0.f};
  f16x8 bf[2][4];
  #pragma unroll
  for(int p=0;p<2;p++)
    stage16((const char*)pl[p] + abyte + w*16, lds + 0*8192 + (p*4+w)*1024);
  SB;
  #pragma unroll
  for(int ct=0;ct<4;ct++){
    int c = w*64 + ct*16 + l15;
    bf[0][ct] = *(const f16x8*)(Bp + ((unsigned)(0*256 + c)*4 + q)*8);
  }
  SB;
  #pragma unroll
  for(int kb=0;kb<8;kb++){
    const int cur = kb%3, nxtb = (kb+1)%3, rB = kb&1;
    if(kb<7){
      #pragma unroll
      for(int p=0;p<2;p++)
        stage16((const char*)pl[p] + abyte + (kb+1)*64 + w*16, lds + nxtb*8192 + (p*4+w)*1024);
      SB;
      #pragma unroll
      for(int ct=0;ct<4;ct++){
        int c = w*64 + ct*16 + l15;
        bf[rB^1][ct] = *(const f16x8*)(Bp + ((unsigned)((kb+1)*256 + c)*4 + q)*8);
      }
      AS_VM(10);
    } else {
      AS_VM(0);
    }
    BAR;
    #pragma unroll
    for(int rt=0;rt<4;rt++){
      f16x8 ah = *(const f16x8*)(lds + cur*8192 + 0*4096 + q*1024 + (rt*16+l15)*16);
      f16x8 al = *(const f16x8*)(lds + cur*8192 + 1*4096 + q*1024 + (rt*16+l15)*16);
      AS_LG;
      #pragma unroll
      for(int ct=0;ct<4;ct++){
        acc[rt][ct] = mfma16(ah, bf[rB][ct], acc[rt][ct]);
        acc[rt][ct] = mfma16(al, bf[rB][ct], acc[rt][ct]);
      }
    }
  }
  #pragma unroll
  for(int rt=0;rt<4;rt++)
    #pragma unroll
    for(int ct=0;ct<4;ct++){
      int c = w*64 + ct*16 + l15;
      float bv = bias[c];
      #pragma unroll
      for(int j=0;j<4;j++){
        int r = m0 + rt*16 + q*4 + j;
        if(r < N_NODESC){
          float v = fmaxf(acc[rt][ct][j] + bv, 0.f);
          f16 hi = (f16)v;
          Chi[(size_t)r*256 + c] = hi;
          Clo[(size_t)r*256 + c] = (f16)(v - (float)hi);
        }
      }
    }
}

// ---------------- fused GRU v5: 4 waves/SIMD tile + B double-buffer ----------------
// grid 2504 = 8 xcd x 313. Block 64r x 32c, wave = 32r x 16c. LDS 2buf x 16KB.
// Per-wave vmem/iter = 4 stage16 + 6 B-loads; steady AS_VM(10) retires S(kb)+B(kb).
__global__ __launch_bounds__(256,4) void k_gru(
    const f16* __restrict__ Xhi, const f16* __restrict__ Xlo,
    const f16* __restrict__ Hhi, const f16* __restrict__ Hlo,
    f16* __restrict__ Nhi, f16* __restrict__ Nlo,
    const f16* __restrict__ Wi, const f16* __restrict__ Wh,
    const float* __restrict__ bih, const float* __restrict__ bhh){
  __shared__ f16x8 ldsv[2048];                 // 32KB
  char* lds = (char*)ldsv;
  const int bid = blockIdx.x;
  const int xcd = bid & 7, j = bid >> 3;       // 2504 = 8*313
  const int nid = xcd*313 + j;
  const int rp = nid >> 3;
  const int cb = nid & 7;
  const int m0 = rp*64;
  const int tid = threadIdx.x, lane = tid&63, w = tid>>6, l15 = lane&15, q = lane>>4;
  const int cc = cb*32 + (w>>1)*16 + l15;      // output col [0,256)
  const int rbase = (w&1)*32;                  // wave row offset in panel
  int rg = m0 + lane; if(rg > N_NODESC-1) rg = N_NODESC-1;
  const f16* pw = (w==0)?Xhi:((w==1)?Xlo:((w==2)?Hhi:Hlo));
  const char* pwc = (const char*)pw + (size_t)rg*512;   // row byte base
  f32x4 acc[6][2];
  #pragma unroll
  for(int m=0;m<6;m++)
    #pragma unroll
    for(int rt=0;rt<2;rt++) acc[m][rt] = (f32x4){0.f,0.f,0.f,0.f};
  const unsigned wbase = (unsigned)cc*32 + q*8;   // f16 units; +gate*8192 +kb*24576
  f16x8 breg[2][6];
  // prologue: S(0), B(0)
  #pragma unroll
  for(int qq=0;qq<4;qq++)
    stage16(pwc + qq*16, lds + w*4096 + qq*1024 + lane*16);
  SB;
  {
    breg[0][0] = *(const f16x8*)(Wi + wbase);
    breg[0][1] = *(const f16x8*)(Wi + wbase + 8192);
    breg[0][2] = *(const f16x8*)(Wi + wbase + 16384);
    breg[0][3] = *(const f16x8*)(Wh + wbase);
    breg[0][4] = *(const f16x8*)(Wh + wbase + 8192);
    breg[0][5] = *(const f16x8*)(Wh + wbase + 16384);
  }
  SB;
  #pragma unroll
  for(int kb=0;kb<8;kb++){
    const int rB = kb&1;
    if(kb<7){
      #pragma unroll
      for(int qq=0;qq<4;qq++)
        stage16(pwc + (kb+1)*64 + qq*16, lds + (rB^1)*16384 + w*4096 + qq*1024 + lane*16);
      SB;
      unsigned wo = wbase + (unsigned)(kb+1)*24576u;
      breg[rB^1][0] = *(const f16x8*)(Wi + wo);
      breg[rB^1][1] = *(const f16x8*)(Wi + wo + 8192);
      breg[rB^1][2] = *(const f16x8*)(Wi + wo + 16384);
      breg[rB^1][3] = *(const f16x8*)(Wh + wo);
      breg[rB^1][4] = *(const f16x8*)(Wh + wo + 8192);
      breg[rB^1][5] = *(const f16x8*)(Wh + wo + 16384);
      SB;
      AS_VM(10);
    } else {
      AS_VM(0);
    }
    BAR;
    #pragma unroll
    for(int rt=0;rt<2;rt++){
      const int ro = rB*16384 + q*1024 + (rbase + rt*16 + l15)*16;
      f16x8 axh = *(const f16x8*)(lds + ro);
      f16x8 axl = *(const f16x8*)(lds + 4096  + ro);
      f16x8 ahh = *(const f16x8*)(lds + 8192  + ro);
      f16x8 ahl = *(const f16x8*)(lds + 12288 + ro);
      __builtin_amdgcn_s_setprio(1);
      acc[0][rt] = mfma16(axh, breg[rB][0], acc[0][rt]);
      acc[0][rt] = mfma16(axl, breg[rB][0], acc[0][rt]);
      acc[1][rt] = mfma16(axh, breg[rB][1], acc[1][rt]);
      acc[1][rt] = mfma16(axl, breg[rB][1], acc[1][rt]);
      acc[2][rt] = mfma16(axh, breg[rB][2], acc[2][rt]);
      acc[2][rt] = mfma16(axl, breg[rB][2], acc[2][rt]);
      acc[3][rt] = mfma16(ahh, breg[rB][3], acc[3][rt]);
      acc[3][rt] = mfma16(ahl, breg[rB][3], acc[3][rt]);
      acc[4][rt] = mfma16(ahh, breg[rB][4], acc[4][rt]);
      acc[4][rt] = mfma16(ahl, breg[rB][4], acc[4][rt]);
      acc[5][rt] = mfma16(ahh, breg[rB][5], acc[5][rt]);
      acc[5][rt] = mfma16(ahl, breg[rB][5], acc[5][rt]);
      __builtin_amdgcn_s_setprio(0);
    }
    BAR;
  }
  float bir=bih[cc], biz=bih[cc+256], bin=bih[cc+512];
  float bhr=bhh[cc], bhz=bhh[cc+256], bhn=bhh[cc+512];
  #pragma unroll
  for(int rt=0;rt<2;rt++){
    #pragma unroll
    for(int jj=0;jj<4;jj++){
      int r = m0 + rbase + rt*16 + q*4 + jj;
      if(r < N_NODESC){
        float ir=acc[0][rt][jj], iz=acc[1][rt][jj], in_=acc[2][rt][jj];
        float hr=acc[3][rt][jj], hz=acc[4][rt][jj], hn=acc[5][rt][jj];
        float rgt = sigm(ir+bir + hr+bhr);
        float zg = sigm(iz+biz + hz+bhz);
        float ng = tanh_(in_+bin + rgt*(hn+bhn));
        float ho = (float)Hhi[(size_t)r*256 + cc] + (float)Hlo[(size_t)r*256 + cc];
        float v = (1.f-zg)*ng + zg*ho;
        f16 hi = (f16)v;
        Nhi[(size_t)r*256 + cc] = hi;
        Nlo[(size_t)r*256 + cc] = (f16)(v - (float)hi);
      }
    }
  }
}

// ---------------- projection: K=256, N=64, pipelined ----------------
__global__ __launch_bounds__(256,2) void k_proj(const f16* __restrict__ Ahi, const f16* __restrict__ Alo,
    const f16* __restrict__ Bp, const float* __restrict__ bias, float* __restrict__ C){
  __shared__ f16x8 ldsv[1536];                 // 3 x 8KB
  char* lds = (char*)ldsv;
  const int tid = threadIdx.x, lane = tid&63, w = tid>>6, l15 = lane&15, q = lane>>4;
  const int m0 = blockIdx.x*64;
  const int cc = w*16 + l15;
  int rg = m0 + lane; if(rg > N_NODESC-1) rg = N_NODESC-1;
  const size_t abyte = (size_t)rg*512;
  const f16* pl[2] = {Ahi, Alo};
  f32x4 acc[4];
  #pragma unroll
  for(int rt=0;rt<4;rt++) acc[rt] = (f32x4){0.f,0.f,0.f,0.f};
  f16x8 bf[2];
  #pragma unroll
  for(int p=0;p<2;p++)
    stage16((const char*)pl[p] + abyte + w*16, lds + 0*8192 + (p*4+w)*1024);
  SB;
  bf[0] = *(const f16x8*)(Bp + ((unsigned)(0*64 + cc)*4 + q)*8);
  SB;
  #pragma unroll
  for(int kb=0;kb<8;kb++){
    const int cur = kb%3, nxtb = (kb+1)%3, rB = kb&1;
    if(kb<7){
      #pragma unroll
      for(int p=0;p<2;p++)
        stage16((const char*)pl[p] + abyte + (kb+1)*64 + w*16, lds + nxtb*8192 + (p*4+w)*1024);
      SB;
      bf[rB^1] = *(const f16x8*)(Bp + ((unsigned)((kb+1)*64 + cc)*4 + q)*8);
      AS_VM(4);
    } else {
      AS_VM(0);
    }
    BAR;
    #pragma unroll
    for(int rt=0;rt<4;rt++){
      f16x8 ah = *(const f16x8*)(lds + cur*8192 + 0*4096 + q*1024 + (rt*16+l15)*16);
      f16x8 al = *(const f16x8*)(lds + cur*8192 + 1*4096 + q*1024 + (rt*16+l15)*16);
      AS_LG;
      acc[rt] = mfma16(ah, bf[rB], acc[rt]);
      acc[rt] = mfma16(al, bf[rB], acc[rt]);
    }
  }
  #pragma unroll
  for(int rt=0;rt<4;rt++){
    float bv = bias[cc];
    #pragma unroll
    for(int j=0;j<4;j++){
      int r = m0 + rt*16 + q*4 + j;
      if(r < N_NODESC) C[(size_t)r*64 + cc] = acc[rt][j] + bv;
    }
  }
}

// ---------------- launcher ----------------
extern "C" void kernel_launch(void* const* d_in, const int* in_sizes, int n_in,
                              void* d_out, int out_size, void* d_ws, size_t ws_size,
                              hipStream_t stream){
  const float* x_seq  = (const float*)d_in[0];
  const int*   srcp   = (const int*)  d_in[1];
  const int*   dstp   = (const int*)  d_in[2];
  const float* gcn1_w = (const float*)d_in[3];
  const float* gcn1_b = (const float*)d_in[4];
  const float* gcn2_w = (const float*)d_in[5];
  const float* gcn2_b = (const float*)d_in[6];
  const float* proj_w = (const float*)d_in[7];
  const float* proj_b = (const float*)d_in[8];
  const float* wih[3] = {(const float*)d_in[9],  (const float*)d_in[13], (const float*)d_in[17]};
  const float* whh[3] = {(const float*)d_in[10], (const float*)d_in[14], (const float*)d_in[18]};
  const float* bih[3] = {(const float*)d_in[11], (const float*)d_in[15], (const float*)d_in[19]};
  const float* bhh[3] = {(const float*)d_in[12], (const float*)d_in[16], (const float*)d_in[20]};
  float* out = (float*)d_out;

  const size_t NP = (size_t)N_NODESC*256;
  char* p = (char*)d_ws;
  auto alloc = [&](size_t bytes)->char*{ char* r = p; p += (bytes + 255) & ~(size_t)255; return r; };
  int*   deg_cnt = (int*)  alloc((size_t)2*N_NODESC*4);
  int*   cursor  = deg_cnt + N_NODESC;
  int*   row_ptr = (int*)  alloc((size_t)(N_NODESC+1)*4);
  float* deg_inv = (float*)alloc((size_t)N_NODESC*4);
  float* deg_is  = (float*)alloc((size_t)N_NODESC*4);
  int*   colv    = (int*)  alloc((size_t)N_EDGESC*4);
  float* normv   = (float*)alloc((size_t)N_EDGESC*4);
  f16* z64h = (f16*)alloc((size_t)N_NODESC*64*2);
  f16* z64l = (f16*)alloc((size_t)N_NODESC*64*2);
  f16* x1   = (f16*)alloc(NP*2);
  f16* xah  = (f16*)alloc(NP*2);
  f16* xal  = (f16*)alloc(NP*2);
  f16* hbuf = (f16*)alloc((size_t)2*3*2*NP*2);
  f16* pk_gcn1 = (f16*)alloc((size_t)64*256*2);
  f16* pk_gcn2 = (f16*)alloc((size_t)256*256*2);
  f16* pk_proj = (f16*)alloc((size_t)256*64*2);
  f16* pk_wi[3]; f16* pk_wh[3];
  for(int i=0;i<3;i++){ pk_wi[i]=(f16*)alloc((size_t)256*768*2); pk_wh[i]=(f16*)alloc((size_t)256*768*2); }

  hipMemsetAsync(deg_cnt, 0, (size_t)2*N_NODESC*4, stream);
  hipMemsetAsync(hbuf,    0, (size_t)3*2*NP*2, stream);

  k_hist<<<2500,256,0,stream>>>(dstp, deg_cnt);
  k_scan<<<1,1024,0,stream>>>(deg_cnt, row_ptr, deg_inv, deg_is);
  k_fill<<<2500,256,0,stream>>>(srcp, dstp, row_ptr, cursor, deg_is, colv, normv);

  k_pack<<<64, 256,0,stream>>>(gcn1_w, pk_gcn1, 64, 256, 0);
  k_pack<<<256,256,0,stream>>>(gcn2_w, pk_gcn2, 256,256, 0);
  k_pack<<<64, 256,0,stream>>>(proj_w, pk_proj, 256, 64, 0);
  for(int i=0;i<3;i++){
    k_pack<<<768,256,0,stream>>>(wih[i], pk_wi[i], 256, 768, 1);
    k_pack<<<768,256,0,stream>>>(whh[i], pk_wh[i], 256, 768, 1);
  }

  auto Hh = [&](int slot, int g)->f16*{ return hbuf + ((size_t)(slot*3+g)*2 + 0)*NP; };
  auto Hl = [&](int slot, int g)->f16*{ return hbuf + ((size_t)(slot*3+g)*2 + 1)*NP; };

  for(int s=0; s<18; s++){
    const float* xt;
    if(s < 12)       xt = x_seq + (size_t)s*N_NODESC*64;
    else if(s == 12) xt = x_seq + (size_t)11*N_NODESC*64;
    else             xt = out   + (size_t)(s-13)*N_NODESC*64;
    int cur = s&1, nxt = cur^1;

    k_agg64 <<<5000,256,0,stream>>>(xt, row_ptr, colv, normv, deg_inv, z64h, z64l);
    k_gcn1  <<<313, 256,0,stream>>>(z64h, z64l, pk_gcn1, gcn1_b, x1);
    k_agg256<<<5000,256,0,stream>>>(x1, row_ptr, colv, normv, deg_inv, xah, xal);
    k_gcn2  <<<313, 256,0,stream>>>(xah, xal, pk_gcn2, gcn2_b, xah, xal);

    k_gru<<<2504,256,0,stream>>>(xah, xal,           Hh(cur,0),Hl(cur,0), Hh(nxt,0),Hl(nxt,0), pk_wi[0], pk_wh[0], bih[0], bhh[0]);
    k_gru<<<2504,256,0,stream>>>(Hh(nxt,0),Hl(nxt,0),Hh(cur,1),Hl(cur,1), Hh(nxt,1),Hl(nxt,1), pk_wi[1], pk_wh[1], bih[1], bhh[1]);
    k_gru<<<2504,256,0,stream>>>(Hh(nxt,1),Hl(nxt,1),Hh(cur,2),Hl(cur,2), Hh(nxt,2),Hl(nxt,2), pk_wi[2], pk_wh[2], bih[2], bhh[2]);

    if(s >= 12)
      k_proj<<<313,256,0,stream>>>(Hh(nxt,2), Hl(nxt,2), pk_proj, proj_b, out + (size_t)(s-12)*N_NODESC*64);
  }
}

// Round 9
// 3862.630 us; speedup vs baseline: 1.6423x; 1.6423x over previous
//
#include <hip/hip_runtime.h>

#define N_NODESC 20000
#define N_EDGESC 640000

typedef _Float16 f16;
typedef __attribute__((ext_vector_type(4))) _Float16 f16x4;
typedef __attribute__((ext_vector_type(8))) _Float16 f16x8;
typedef __attribute__((ext_vector_type(4))) float f32x4;

__device__ __forceinline__ f32x4 mfma16(f16x8 a, f16x8 b, f32x4 c){
  return __builtin_amdgcn_mfma_f32_16x16x32_f16(a, b, c, 0, 0, 0);
}
__device__ __forceinline__ float sigm(float x){ return 1.f/(1.f+__expf(-x)); }
__device__ __forceinline__ float tanh_(float x){
  x = fminf(fmaxf(x, -15.f), 15.f);
  float e = __expf(-2.f*x);
  return (1.f - e)/(1.f + e);
}
__device__ __forceinline__ void stage16(const void* g, void* l){
  __builtin_amdgcn_global_load_lds((const __attribute__((address_space(1))) unsigned int*)g,
                                   (__attribute__((address_space(3))) unsigned int*)l, 16, 0, 0);
}
#define SB       __builtin_amdgcn_sched_barrier(0)
#define AS_VM(n) do{ asm volatile("s_waitcnt vmcnt(" #n ")" ::: "memory"); SB; }while(0)
#define BAR      do{ __builtin_amdgcn_s_barrier(); SB; }while(0)

// ---------------- CSR construction ----------------
__global__ __launch_bounds__(256) void k_hist(const int* __restrict__ dst, int* __restrict__ cnt){
  int e = blockIdx.x*256 + threadIdx.x;
  if(e < N_EDGESC) atomicAdd(&cnt[dst[e]], 1);
}

__global__ __launch_bounds__(1024) void k_scan(const int* __restrict__ cnt, int* __restrict__ row_ptr,
    float* __restrict__ deg_inv, float* __restrict__ deg_is){
  __shared__ int wsum[16];
  int t = threadIdx.x;
  int base = t*20;
  int loc[20]; int s = 0;
  #pragma unroll
  for(int i=0;i<20;i++){ int idx=base+i; int v = (idx<N_NODESC)? cnt[idx] : 0; loc[i]=s; s+=v; }
  int lane = t&63, wv = t>>6;
  int incl = s;
  #pragma unroll
  for(int off=1; off<64; off<<=1){ int u = __shfl_up(incl, off); if(lane>=off) incl += u; }
  if(lane==63) wsum[wv]=incl;
  __syncthreads();
  int woff=0;
  for(int i=0;i<wv;i++) woff += wsum[i];
  int excl = woff + incl - s;
  #pragma unroll
  for(int i=0;i<20;i++){
    int idx=base+i;
    if(idx<N_NODESC){
      row_ptr[idx] = excl + loc[i];
      float d = (float)(cnt[idx]+1);
      deg_inv[idx] = 1.f/d;
      deg_is[idx]  = rsqrtf(d);
    }
  }
  if(t==1023) row_ptr[N_NODESC] = woff + incl;
}

__global__ __launch_bounds__(256) void k_fill(const int* __restrict__ src, const int* __restrict__ dst,
    const int* __restrict__ row_ptr, int* __restrict__ cursor, const float* __restrict__ deg_is,
    int* __restrict__ colv, float* __restrict__ normv){
  int e = blockIdx.x*256 + threadIdx.x;
  if(e >= N_EDGESC) return;
  int d = dst[e], s = src[e];
  int p = atomicAdd(&cursor[d], 1);
  int idx = row_ptr[d] + p;
  colv[idx] = s;
  normv[idx] = deg_is[s]*deg_is[d];
}

// ---------------- weight packing (f16, MFMA B-fragment order) ----------------
__global__ __launch_bounds__(256) void k_pack(const float* __restrict__ w, f16* __restrict__ dstp,
    int K, int NO, int trans){
  int t = blockIdx.x*256 + threadIdx.x;
  if(t >= K*NO) return;
  int i = t&7, g = (t>>3)&3, rest = t>>5;
  int c = rest % NO, kb = rest / NO;
  int k = kb*32 + g*8 + i;
  float v = trans ? w[(size_t)c*K + k] : w[(size_t)k*NO + c];
  dstp[t] = (f16)v;
}

// ---------------- aggregation ----------------
__global__ __launch_bounds__(256) void k_agg64(const float* __restrict__ x,
    const int* __restrict__ row_ptr, const int* __restrict__ colv,
    const float* __restrict__ normv, const float* __restrict__ deg_inv,
    f16* __restrict__ O){
  int n = (blockIdx.x*256 + threadIdx.x)>>6;
  int c = threadIdx.x&63;
  if(n >= N_NODESC) return;
  float acc = deg_inv[n]*x[(size_t)n*64 + c];
  int e0 = row_ptr[n], e1 = row_ptr[n+1];
  int e = e0;
  for(; e+4<=e1; e+=4){
    int s0=colv[e],s1=colv[e+1],s2=colv[e+2],s3=colv[e+3];
    float w0=normv[e],w1=normv[e+1],w2=normv[e+2],w3=normv[e+3];
    float v0=x[(size_t)s0*64+c], v1=x[(size_t)s1*64+c];
    float v2=x[(size_t)s2*64+c], v3=x[(size_t)s3*64+c];
    acc += w0*v0 + w1*v1 + w2*v2 + w3*v3;
  }
  for(; e<e1; e++) acc += normv[e]*x[(size_t)colv[e]*64+c];
  O[(size_t)n*64+c] = (f16)acc;
}

__global__ __launch_bounds__(256) void k_agg256(const f16* __restrict__ x1,
    const int* __restrict__ row_ptr, const int* __restrict__ colv,
    const float* __restrict__ normv, const float* __restrict__ deg_inv,
    f16* __restrict__ O){
  int n = (blockIdx.x*256 + threadIdx.x)>>6;
  int lane = threadIdx.x&63;
  if(n >= N_NODESC) return;
  const f16x4* xv = (const f16x4*)x1;
  f32x4 acc = __builtin_convertvector(xv[(size_t)n*64 + lane], f32x4) * deg_inv[n];
  int e0 = row_ptr[n], e1 = row_ptr[n+1];
  int e = e0;
  for(; e+4<=e1; e+=4){
    int s0=colv[e],s1=colv[e+1],s2=colv[e+2],s3=colv[e+3];
    float w0=normv[e],w1=normv[e+1],w2=normv[e+2],w3=normv[e+3];
    f32x4 v0=__builtin_convertvector(xv[(size_t)s0*64+lane], f32x4);
    f32x4 v1=__builtin_convertvector(xv[(size_t)s1*64+lane], f32x4);
    f32x4 v2=__builtin_convertvector(xv[(size_t)s2*64+lane], f32x4);
    f32x4 v3=__builtin_convertvector(xv[(size_t)s3*64+lane], f32x4);
    acc += v0*w0; acc += v1*w1; acc += v2*w2; acc += v3*w3;
  }
  for(; e<e1; e++) acc += __builtin_convertvector(xv[(size_t)colv[e]*64+lane], f32x4)*normv[e];
  ((f16x4*)O)[(size_t)n*64+lane] = __builtin_convertvector(acc, f16x4);
}

// ---------------- GCN1: K=64, N=256, single-plane A, single-stage LDS ----------------
__global__ __launch_bounds__(256) void k_gcn1(const f16* __restrict__ A,
    const f16* __restrict__ Bp, const float* __restrict__ bias, f16* __restrict__ C){
  __shared__ f16x8 ldsv[512];                  // [kb:2][q:4][row:64][16B] = 8KB
  char* lds = (char*)ldsv;
  const int tid = threadIdx.x, lane = tid&63, w = tid>>6, l15 = lane&15, q = lane>>4;
  const int m0 = blockIdx.x*64;
  int rg = m0 + lane; if(rg > N_NODESC-1) rg = N_NODESC-1;
  #pragma unroll
  for(int i=0;i<2;i++){
    int region = i*4 + w;                      // kbb = region>>2, qq = region&3
    int kbb = region>>2, qq = region&3;
    stage16((const char*)A + (size_t)rg*128 + kbb*64 + qq*16, lds + region*1024 + lane*16);
  }
  AS_VM(0);
  BAR;
  f32x4 acc[4][4];
  #pragma unroll
  for(int rt=0;rt<4;rt++)
    #pragma unroll
    for(int ct=0;ct<4;ct++) acc[rt][ct] = (f32x4){0.f,0.f,0.f,0.f};
  #pragma unroll
  for(int kb=0;kb<2;kb++){
    f16x8 bf[4];
    #pragma unroll
    for(int ct=0;ct<4;ct++){
      int c = w*64 + ct*16 + l15;
      bf[ct] = *(const f16x8*)(Bp + ((unsigned)(kb*256 + c)*4 + q)*8);
    }
    #pragma unroll
    for(int rt=0;rt<4;rt++){
      f16x8 ah = *(const f16x8*)(lds + (kb*4+q)*1024 + (rt*16+l15)*16);
      #pragma unroll
      for(int ct=0;ct<4;ct++)
        acc[rt][ct] = mfma16(ah, bf[ct], acc[rt][ct]);
    }
  }
  #pragma unroll
  for(int rt=0;rt<4;rt++)
    #pragma unroll
    for(int ct=0;ct<4;ct++){
      int c = w*64 + ct*16 + l15;
      float bv = bias[c];
      #pragma unroll
      for(int j=0;j<4;j++){
        int r = m0 + rt*16 + q*4 + j;
        if(r < N_NODESC) C[(size_t)r*256 + c] = (f16)fmaxf(acc[rt][ct][j] + bv, 0.f);
      }
    }
}

// ---------------- GCN2: K=256, single-plane A, triple-buffer, counted vmcnt ----------------
// per-iter vmem/wave: 1 stage + 4 B. At wait in iter k, newer-than-B(k) = 1+4 = 5.
__global__ __launch_bounds__(256,2) void k_gcn2(const f16* __restrict__ A,
    const f16* __restrict__ Bp, const float* __restrict__ bias, f16* __restrict__ C){
  __shared__ f16x8 ldsv[768];                  // 3 bufs x 4KB = 12KB
  char* lds = (char*)ldsv;
  const int tid = threadIdx.x, lane = tid&63, w = tid>>6, l15 = lane&15, q = lane>>4;
  const int m0 = blockIdx.x*64;
  int rg = m0 + lane; if(rg > N_NODESC-1) rg = N_NODESC-1;
  const size_t abyte = (size_t)rg*512;
  f32x4 acc[4][4];
  #pragma unroll
  for(int rt=0;rt<4;rt++)
    #pragma unroll
    for(int ct=0;ct<4;ct++) acc[rt][ct] = (f32x4){0.f,0.f,0.f,0.f};
  f16x8 bf[2][4];
  stage16((const char*)A + abyte + w*16, lds + 0*4096 + w*1024 + lane*16);
  SB;
  #pragma unroll
  for(int ct=0;ct<4;ct++){
    int c = w*64 + ct*16 + l15;
    bf[0][ct] = *(const f16x8*)(Bp + ((unsigned)(0*256 + c)*4 + q)*8);
  }
  SB;
  #pragma unroll
  for(int kb=0;kb<8;kb++){
    const int cur = kb%3, nxtb = (kb+1)%3, rB = kb&1;
    if(kb<7){
      stage16((const char*)A + abyte + (kb+1)*64 + w*16, lds + nxtb*4096 + w*1024 + lane*16);
      SB;
      #pragma unroll
      for(int ct=0;ct<4;ct++){
        int c = w*64 + ct*16 + l15;
        bf[rB^1][ct] = *(const f16x8*)(Bp + ((unsigned)((kb+1)*256 + c)*4 + q)*8);
      }
      AS_VM(5);
    } else {
      AS_VM(0);
    }
    BAR;
    #pragma unroll
    for(int rt=0;rt<4;rt++){
      f16x8 ah = *(const f16x8*)(lds + cur*4096 + q*1024 + (rt*16+l15)*16);
      #pragma unroll
      for(int ct=0;ct<4;ct++)
        acc[rt][ct] = mfma16(ah, bf[rB][ct], acc[rt][ct]);
    }
  }
  #pragma unroll
  for(int rt=0;rt<4;rt++)
    #pragma unroll
    for(int ct=0;ct<4;ct++){
      int c = w*64 + ct*16 + l15;
      float bv = bias[c];
      #pragma unroll
      for(int j=0;j<4;j++){
        int r = m0 + rt*16 + q*4 + j;
        if(r < N_NODESC) C[(size_t)r*256 + c] = (f16)fmaxf(acc[rt][ct][j] + bv, 0.f);
      }
    }
}

// ---------------- fused GRU v6: single-f16 X,H; R5 schedule (3-buf, 1 bar/iter) ----------
// grid 1252 bijective-XCD. Block 64r x 64c, wave = 64r x 16c, acc[6][4].
// LDS: 3 bufs x [plane:2][chunk:4][row:64][16B] = 24KB. Per-iter vmem/wave: 2 stage + 6 B.
// At wait in iter k: newer-than-B(k) = 2+6 = 8 -> AS_VM(8).
__global__ __launch_bounds__(256,2) void k_gru(
    const f16* __restrict__ X, const f16* __restrict__ H, f16* __restrict__ Nh,
    const f16* __restrict__ Wi, const f16* __restrict__ Wh,
    const float* __restrict__ bih, const float* __restrict__ bhh){
  __shared__ f16x8 ldsv[1536];                 // 24KB
  char* lds = (char*)ldsv;
  const int NB = 1252, QQ = NB>>3, RR = NB&7;  // 156, 4
  int bid = blockIdx.x;
  int xcd = bid & 7, jj = bid >> 3;
  int nid = (xcd < RR) ? xcd*(QQ+1) + jj : RR*(QQ+1) + (xcd-RR)*QQ + jj;
  const int m0 = (nid>>2)*64;
  const int cb = nid&3;
  const int tid = threadIdx.x, lane = tid&63, w = tid>>6, l15 = lane&15, q = lane>>4;
  const int cc = cb*64 + w*16 + l15;
  int rg = m0 + lane; if(rg > N_NODESC-1) rg = N_NODESC-1;
  const size_t abyte = (size_t)rg*512;
  const f16* pl[2] = {X, H};
  f32x4 acc[6][4];
  #pragma unroll
  for(int m=0;m<6;m++)
    #pragma unroll
    for(int rt=0;rt<4;rt++) acc[m][rt] = (f32x4){0.f,0.f,0.f,0.f};
  const unsigned wbase = (unsigned)cc*32 + q*8;   // f16 units; +gate*8192 +kb*24576
  f16x8 breg[2][6];
  // staging: wave w does (p,c) pairs {2w, 2w+1}: p=pc>>2, c=pc&3
  #pragma unroll
  for(int i=0;i<2;i++){
    int pc = w*2 + i; int p = pc>>2, c = pc&3;
    stage16((const char*)pl[p] + abyte + c*16, lds + p*4096 + c*1024 + lane*16);
  }
  SB;
  {
    breg[0][0] = *(const f16x8*)(Wi + wbase);
    breg[0][1] = *(const f16x8*)(Wi + wbase + 8192);
    breg[0][2] = *(const f16x8*)(Wi + wbase + 16384);
    breg[0][3] = *(const f16x8*)(Wh + wbase);
    breg[0][4] = *(const f16x8*)(Wh + wbase + 8192);
    breg[0][5] = *(const f16x8*)(Wh + wbase + 16384);
  }
  SB;
  #pragma unroll
  for(int kb=0;kb<8;kb++){
    const int cur = kb%3, nxtb = (kb+1)%3, rB = kb&1;
    if(kb<7){
      #pragma unroll
      for(int i=0;i<2;i++){
        int pc = w*2 + i; int p = pc>>2, c = pc&3;
        stage16((const char*)pl[p] + abyte + (kb+1)*64 + c*16, lds + nxtb*8192 + p*4096 + c*1024 + lane*16);
      }
      SB;
      unsigned wo = wbase + (unsigned)(kb+1)*24576u;
      breg[rB^1][0] = *(const f16x8*)(Wi + wo);
      breg[rB^1][1] = *(const f16x8*)(Wi + wo + 8192);
      breg[rB^1][2] = *(const f16x8*)(Wi + wo + 16384);
      breg[rB^1][3] = *(const f16x8*)(Wh + wo);
      breg[rB^1][4] = *(const f16x8*)(Wh + wo + 8192);
      breg[rB^1][5] = *(const f16x8*)(Wh + wo + 16384);
      SB;
      AS_VM(8);
    } else {
      AS_VM(0);
    }
    BAR;
    #pragma unroll
    for(int rt=0;rt<4;rt++){
      const int ro = cur*8192 + q*1024 + (rt*16+l15)*16;
      f16x8 ax = *(const f16x8*)(lds + ro);
      f16x8 ah = *(const f16x8*)(lds + 4096 + ro);
      acc[0][rt] = mfma16(ax, breg[rB][0], acc[0][rt]);
      acc[1][rt] = mfma16(ax, breg[rB][1], acc[1][rt]);
      acc[2][rt] = mfma16(ax, breg[rB][2], acc[2][rt]);
      acc[3][rt] = mfma16(ah, breg[rB][3], acc[3][rt]);
      acc[4][rt] = mfma16(ah, breg[rB][4], acc[4][rt]);
      acc[5][rt] = mfma16(ah, breg[rB][5], acc[5][rt]);
    }
  }
  float bir=bih[cc], biz=bih[cc+256], bin=bih[cc+512];
  float bhr=bhh[cc], bhz=bhh[cc+256], bhn=bhh[cc+512];
  #pragma unroll
  for(int rt=0;rt<4;rt++){
    #pragma unroll
    for(int j=0;j<4;j++){
      int r = m0 + rt*16 + q*4 + j;
      if(r < N_NODESC){
        float ir=acc[0][rt][j], iz=acc[1][rt][j], in_=acc[2][rt][j];
        float hr=acc[3][rt][j], hz=acc[4][rt][j], hn=acc[5][rt][j];
        float rgt = sigm(ir+bir + hr+bhr);
        float zg = sigm(iz+biz + hz+bhz);
        float ng = tanh_(in_+bin + rgt*(hn+bhn));
        float ho = (float)H[(size_t)r*256 + cc];
        float v = (1.f-zg)*ng + zg*ho;
        Nh[(size_t)r*256 + cc] = (f16)v;
      }
    }
  }
}

// ---------------- projection: K=256, N=64, single-plane A, f32 out ----------------
// per-iter vmem/wave: 1 stage + 1 B -> newer-than-B(k) = 2 -> AS_VM(2).
__global__ __launch_bounds__(256,2) void k_proj(const f16* __restrict__ A,
    const f16* __restrict__ Bp, const float* __restrict__ bias, float* __restrict__ C){
  __shared__ f16x8 ldsv[768];                  // 3 x 4KB
  char* lds = (char*)ldsv;
  const int tid = threadIdx.x, lane = tid&63, w = tid>>6, l15 = lane&15, q = lane>>4;
  const int m0 = blockIdx.x*64;
  const int cc = w*16 + l15;
  int rg = m0 + lane; if(rg > N_NODESC-1) rg = N_NODESC-1;
  const size_t abyte = (size_t)rg*512;
  f32x4 acc[4];
  #pragma unroll
  for(int rt=0;rt<4;rt++) acc[rt] = (f32x4){0.f,0.f,0.f,0.f};
  f16x8 bf[2];
  stage16((const char*)A + abyte + w*16, lds + 0*4096 + w*1024 + lane*16);
  SB;
  bf[0] = *(const f16x8*)(Bp + ((unsigned)(0*64 + cc)*4 + q)*8);
  SB;
  #pragma unroll
  for(int kb=0;kb<8;kb++){
    const int cur = kb%3, nxtb = (kb+1)%3, rB = kb&1;
    if(kb<7){
      stage16((const char*)A + abyte + (kb+1)*64 + w*16, lds + nxtb*4096 + w*1024 + lane*16);
      SB;
      bf[rB^1] = *(const f16x8*)(Bp + ((unsigned)((kb+1)*64 + cc)*4 + q)*8);
      AS_VM(2);
    } else {
      AS_VM(0);
    }
    BAR;
    #pragma unroll
    for(int rt=0;rt<4;rt++){
      f16x8 ah = *(const f16x8*)(lds + cur*4096 + q*1024 + (rt*16+l15)*16);
      acc[rt] = mfma16(ah, bf[rB], acc[rt]);
    }
  }
  #pragma unroll
  for(int rt=0;rt<4;rt++){
    float bv = bias[cc];
    #pragma unroll
    for(int j=0;j<4;j++){
      int r = m0 + rt*16 + q*4 + j;
      if(r < N_NODESC) C[(size_t)r*64 + cc] = acc[rt][j] + bv;
    }
  }
}

// ---------------- launcher ----------------
extern "C" void kernel_launch(void* const* d_in, const int* in_sizes, int n_in,
                              void* d_out, int out_size, void* d_ws, size_t ws_size,
                              hipStream_t stream){
  const float* x_seq  = (const float*)d_in[0];
  const int*   srcp   = (const int*)  d_in[1];
  const int*   dstp   = (const int*)  d_in[2];
  const float* gcn1_w = (const float*)d_in[3];
  const float* gcn1_b = (const float*)d_in[4];
  const float* gcn2_w = (const float*)d_in[5];
  const float* gcn2_b = (const float*)d_in[6];
  const float* proj_w = (const float*)d_in[7];
  const float* proj_b = (const float*)d_in[8];
  const float* wih[3] = {(const float*)d_in[9],  (const float*)d_in[13], (const float*)d_in[17]};
  const float* whh[3] = {(const float*)d_in[10], (const float*)d_in[14], (const float*)d_in[18]};
  const float* bih[3] = {(const float*)d_in[11], (const float*)d_in[15], (const float*)d_in[19]};
  const float* bhh[3] = {(const float*)d_in[12], (const float*)d_in[16], (const float*)d_in[20]};
  float* out = (float*)d_out;

  const size_t NP = (size_t)N_NODESC*256;
  char* p = (char*)d_ws;
  auto alloc = [&](size_t bytes)->char*{ char* r = p; p += (bytes + 255) & ~(size_t)255; return r; };
  int*   deg_cnt = (int*)  alloc((size_t)2*N_NODESC*4);
  int*   cursor  = deg_cnt + N_NODESC;
  int*   row_ptr = (int*)  alloc((size_t)(N_NODESC+1)*4);
  float* deg_inv = (float*)alloc((size_t)N_NODESC*4);
  float* deg_is  = (float*)alloc((size_t)N_NODESC*4);
  int*   colv    = (int*)  alloc((size_t)N_EDGESC*4);
  float* normv   = (float*)alloc((size_t)N_EDGESC*4);
  f16* z64  = (f16*)alloc((size_t)N_NODESC*64*2);
  f16* x1   = (f16*)alloc(NP*2);
  f16* xa   = (f16*)alloc(NP*2);
  f16* hbuf = (f16*)alloc((size_t)2*3*NP*2);     // [slot][gru][N*256]
  f16* pk_gcn1 = (f16*)alloc((size_t)64*256*2);
  f16* pk_gcn2 = (f16*)alloc((size_t)256*256*2);
  f16* pk_proj = (f16*)alloc((size_t)256*64*2);
  f16* pk_wi[3]; f16* pk_wh[3];
  for(int i=0;i<3;i++){ pk_wi[i]=(f16*)alloc((size_t)256*768*2); pk_wh[i]=(f16*)alloc((size_t)256*768*2); }

  hipMemsetAsync(deg_cnt, 0, (size_t)2*N_NODESC*4, stream);
  hipMemsetAsync(hbuf,    0, (size_t)3*NP*2, stream);   // slot 0 = h0

  k_hist<<<2500,256,0,stream>>>(dstp, deg_cnt);
  k_scan<<<1,1024,0,stream>>>(deg_cnt, row_ptr, deg_inv, deg_is);
  k_fill<<<2500,256,0,stream>>>(srcp, dstp, row_ptr, cursor, deg_is, colv, normv);

  k_pack<<<64, 256,0,stream>>>(gcn1_w, pk_gcn1, 64, 256, 0);
  k_pack<<<256,256,0,stream>>>(gcn2_w, pk_gcn2, 256,256, 0);
  k_pack<<<64, 256,0,stream>>>(proj_w, pk_proj, 256, 64, 0);
  for(int i=0;i<3;i++){
    k_pack<<<768,256,0,stream>>>(wih[i], pk_wi[i], 256, 768, 1);
    k_pack<<<768,256,0,stream>>>(whh[i], pk_wh[i], 256, 768, 1);
  }

  auto Hs = [&](int slot, int g)->f16*{ return hbuf + ((size_t)(slot*3+g))*NP; };

  for(int s=0; s<18; s++){
    const float* xt;
    if(s < 12)       xt = x_seq + (size_t)s*N_NODESC*64;
    else if(s == 12) xt = x_seq + (size_t)11*N_NODESC*64;
    else             xt = out   + (size_t)(s-13)*N_NODESC*64;
    int cur = s&1, nxt = cur^1;

    k_agg64 <<<5000,256,0,stream>>>(xt, row_ptr, colv, normv, deg_inv, z64);
    k_gcn1  <<<313, 256,0,stream>>>(z64, pk_gcn1, gcn1_b, x1);
    k_agg256<<<5000,256,0,stream>>>(x1, row_ptr, colv, normv, deg_inv, xa);
    k_gcn2  <<<313, 256,0,stream>>>(xa, pk_gcn2, gcn2_b, xa);

    k_gru<<<1252,256,0,stream>>>(xa,        Hs(cur,0), Hs(nxt,0), pk_wi[0], pk_wh[0], bih[0], bhh[0]);
    k_gru<<<1252,256,0,stream>>>(Hs(nxt,0), Hs(cur,1), Hs(nxt,1), pk_wi[1], pk_wh[1], bih[1], bhh[1]);
    k_gru<<<1252,256,0,stream>>>(Hs(nxt,1), Hs(cur,2), Hs(nxt,2), pk_wi[2], pk_wh[2], bih[2], bhh[2]);

    if(s >= 12)
      k_proj<<<313,256,0,stream>>>(Hs(nxt,2), pk_proj, proj_b, out + (size_t)(s-12)*N_NODESC*64);
  }
}

// Round 10
// 3805.005 us; speedup vs baseline: 1.6672x; 1.0151x over previous
//
#include <hip/hip_runtime.h>

#define N_NODESC 20000
#define N_EDGESC 640000

typedef _Float16 f16;
typedef __attribute__((ext_vector_type(4))) _Float16 f16x4;
typedef __attribute__((ext_vector_type(8))) _Float16 f16x8;
typedef __attribute__((ext_vector_type(4))) float f32x4;

__device__ __forceinline__ f32x4 mfma16(f16x8 a, f16x8 b, f32x4 c){
  return __builtin_amdgcn_mfma_f32_16x16x32_f16(a, b, c, 0, 0, 0);
}
__device__ __forceinline__ float sigm(float x){ return 1.f/(1.f+__expf(-x)); }
__device__ __forceinline__ float tanh_(float x){
  x = fminf(fmaxf(x, -15.f), 15.f);
  float e = __expf(-2.f*x);
  return (1.f - e)/(1.f + e);
}
__device__ __forceinline__ void stage16(const void* g, void* l){
  __builtin_amdgcn_global_load_lds((const __attribute__((address_space(1))) unsigned int*)g,
                                   (__attribute__((address_space(3))) unsigned int*)l, 16, 0, 0);
}
#define SB       __builtin_amdgcn_sched_barrier(0)
#define AS_VM(n) do{ asm volatile("s_waitcnt vmcnt(" #n ")" ::: "memory"); SB; }while(0)
#define BAR      do{ __builtin_amdgcn_s_barrier(); SB; }while(0)

// ---------------- CSR construction ----------------
__global__ __launch_bounds__(256) void k_hist(const int* __restrict__ dst, int* __restrict__ cnt){
  int e = blockIdx.x*256 + threadIdx.x;
  if(e < N_EDGESC) atomicAdd(&cnt[dst[e]], 1);
}

__global__ __launch_bounds__(1024) void k_scan(const int* __restrict__ cnt, int* __restrict__ row_ptr,
    float* __restrict__ deg_inv, float* __restrict__ deg_is){
  __shared__ int wsum[16];
  int t = threadIdx.x;
  int base = t*20;
  int loc[20]; int s = 0;
  #pragma unroll
  for(int i=0;i<20;i++){ int idx=base+i; int v = (idx<N_NODESC)? cnt[idx] : 0; loc[i]=s; s+=v; }
  int lane = t&63, wv = t>>6;
  int incl = s;
  #pragma unroll
  for(int off=1; off<64; off<<=1){ int u = __shfl_up(incl, off); if(lane>=off) incl += u; }
  if(lane==63) wsum[wv]=incl;
  __syncthreads();
  int woff=0;
  for(int i=0;i<wv;i++) woff += wsum[i];
  int excl = woff + incl - s;
  #pragma unroll
  for(int i=0;i<20;i++){
    int idx=base+i;
    if(idx<N_NODESC){
      row_ptr[idx] = excl + loc[i];
      float d = (float)(cnt[idx]+1);
      deg_inv[idx] = 1.f/d;
      deg_is[idx]  = rsqrtf(d);
    }
  }
  if(t==1023) row_ptr[N_NODESC] = woff + incl;
}

// packed edge record: .x = src index, .y = bitcast(norm)
__global__ __launch_bounds__(256) void k_fill(const int* __restrict__ src, const int* __restrict__ dst,
    const int* __restrict__ row_ptr, int* __restrict__ cursor, const float* __restrict__ deg_is,
    int2* __restrict__ ev){
  int e = blockIdx.x*256 + threadIdx.x;
  if(e >= N_EDGESC) return;
  int d = dst[e], s = src[e];
  int p = atomicAdd(&cursor[d], 1);
  int2 v;
  v.x = s;
  v.y = __float_as_int(deg_is[s]*deg_is[d]);
  ev[row_ptr[d] + p] = v;
}

// ---------------- x_seq f32 -> f16 conversion (once) ----------------
__global__ __launch_bounds__(256) void k_cvt(const float* __restrict__ x, f16* __restrict__ o, int n4){
  int i = blockIdx.x*256 + threadIdx.x;
  if(i >= n4) return;
  f32x4 v = *(const f32x4*)(x + (size_t)i*4);
  *(f16x4*)(o + (size_t)i*4) = __builtin_convertvector(v, f16x4);
}

// ---------------- weight packing (f16, MFMA B-fragment order) ----------------
__global__ __launch_bounds__(256) void k_pack(const float* __restrict__ w, f16* __restrict__ dstp,
    int K, int NO, int trans){
  int t = blockIdx.x*256 + threadIdx.x;
  if(t >= K*NO) return;
  int i = t&7, g = (t>>3)&3, rest = t>>5;
  int c = rest % NO, kb = rest / NO;
  int k = kb*32 + g*8 + i;
  float v = trans ? w[(size_t)c*K + k] : w[(size_t)k*NO + c];
  dstp[t] = (f16)v;
}

// ---------------- aggregation ----------------
__global__ __launch_bounds__(256) void k_agg64(const f16* __restrict__ x,
    const int* __restrict__ row_ptr, const int2* __restrict__ ev,
    const float* __restrict__ deg_inv, f16* __restrict__ O){
  int n = (blockIdx.x*256 + threadIdx.x)>>6;
  int c = threadIdx.x&63;
  if(n >= N_NODESC) return;
  float acc = deg_inv[n]*(float)x[(size_t)n*64 + c];
  int e0 = row_ptr[n], e1 = row_ptr[n+1];
  int e = e0;
  for(; e+4<=e1; e+=4){
    int2 a=ev[e], b=ev[e+1], cc=ev[e+2], d=ev[e+3];
    float v0=(float)x[(size_t)a.x*64+c],  v1=(float)x[(size_t)b.x*64+c];
    float v2=(float)x[(size_t)cc.x*64+c], v3=(float)x[(size_t)d.x*64+c];
    acc += __int_as_float(a.y)*v0 + __int_as_float(b.y)*v1
         + __int_as_float(cc.y)*v2 + __int_as_float(d.y)*v3;
  }
  for(; e<e1; e++){ int2 a=ev[e]; acc += __int_as_float(a.y)*(float)x[(size_t)a.x*64+c]; }
  O[(size_t)n*64+c] = (f16)acc;
}

__global__ __launch_bounds__(256) void k_agg256(const f16* __restrict__ x1,
    const int* __restrict__ row_ptr, const int2* __restrict__ ev,
    const float* __restrict__ deg_inv, f16* __restrict__ O){
  int n = (blockIdx.x*256 + threadIdx.x)>>6;
  int lane = threadIdx.x&63;
  if(n >= N_NODESC) return;
  const f16x4* xv = (const f16x4*)x1;
  f32x4 acc = __builtin_convertvector(xv[(size_t)n*64 + lane], f32x4) * deg_inv[n];
  int e0 = row_ptr[n], e1 = row_ptr[n+1];
  int e = e0;
  for(; e+4<=e1; e+=4){
    int2 a=ev[e], b=ev[e+1], cc=ev[e+2], d=ev[e+3];
    f32x4 v0=__builtin_convertvector(xv[(size_t)a.x*64+lane],  f32x4);
    f32x4 v1=__builtin_convertvector(xv[(size_t)b.x*64+lane],  f32x4);
    f32x4 v2=__builtin_convertvector(xv[(size_t)cc.x*64+lane], f32x4);
    f32x4 v3=__builtin_convertvector(xv[(size_t)d.x*64+lane],  f32x4);
    acc += v0*__int_as_float(a.y); acc += v1*__int_as_float(b.y);
    acc += v2*__int_as_float(cc.y); acc += v3*__int_as_float(d.y);
  }
  for(; e<e1; e++){ int2 a=ev[e];
    acc += __builtin_convertvector(xv[(size_t)a.x*64+lane], f32x4)*__int_as_float(a.y); }
  ((f16x4*)O)[(size_t)n*64+lane] = __builtin_convertvector(acc, f16x4);
}

// ---------------- GCN1: K=64, N=256, single-stage LDS ----------------
__global__ __launch_bounds__(256) void k_gcn1(const f16* __restrict__ A,
    const f16* __restrict__ Bp, const float* __restrict__ bias, f16* __restrict__ C){
  __shared__ f16x8 ldsv[512];                  // [kb:2][q:4][row:64][16B] = 8KB
  char* lds = (char*)ldsv;
  const int tid = threadIdx.x, lane = tid&63, w = tid>>6, l15 = lane&15, q = lane>>4;
  const int m0 = blockIdx.x*64;
  int rg = m0 + lane; if(rg > N_NODESC-1) rg = N_NODESC-1;
  #pragma unroll
  for(int i=0;i<2;i++){
    int region = i*4 + w;
    int kbb = region>>2, qq = region&3;
    stage16((const char*)A + (size_t)rg*128 + kbb*64 + qq*16, lds + region*1024 + lane*16);
  }
  AS_VM(0);
  BAR;
  f32x4 acc[4][4];
  #pragma unroll
  for(int rt=0;rt<4;rt++)
    #pragma unroll
    for(int ct=0;ct<4;ct++) acc[rt][ct] = (f32x4){0.f,0.f,0.f,0.f};
  #pragma unroll
  for(int kb=0;kb<2;kb++){
    f16x8 bf[4];
    #pragma unroll
    for(int ct=0;ct<4;ct++){
      int c = w*64 + ct*16 + l15;
      bf[ct] = *(const f16x8*)(Bp + ((unsigned)(kb*256 + c)*4 + q)*8);
    }
    #pragma unroll
    for(int rt=0;rt<4;rt++){
      f16x8 ah = *(const f16x8*)(lds + (kb*4+q)*1024 + (rt*16+l15)*16);
      #pragma unroll
      for(int ct=0;ct<4;ct++)
        acc[rt][ct] = mfma16(ah, bf[ct], acc[rt][ct]);
    }
  }
  #pragma unroll
  for(int rt=0;rt<4;rt++)
    #pragma unroll
    for(int ct=0;ct<4;ct++){
      int c = w*64 + ct*16 + l15;
      float bv = bias[c];
      #pragma unroll
      for(int j=0;j<4;j++){
        int r = m0 + rt*16 + q*4 + j;
        if(r < N_NODESC) C[(size_t)r*256 + c] = (f16)fmaxf(acc[rt][ct][j] + bv, 0.f);
      }
    }
}

// ---------------- GCN2: K=256, 4-buf LDS, distance-2 staging ----------------
// per-iter: 1 stage + 4 B. newer-than-B(kb): kb<6 -> S(kb+2)+B(kb+1)=5; kb==6 -> 4; kb==7 -> 0.
__global__ __launch_bounds__(256,2) void k_gcn2(const f16* __restrict__ A,
    const f16* __restrict__ Bp, const float* __restrict__ bias, f16* __restrict__ C){
  __shared__ f16x8 ldsv[1024];                 // 4 bufs x 4KB = 16KB
  char* lds = (char*)ldsv;
  const int tid = threadIdx.x, lane = tid&63, w = tid>>6, l15 = lane&15, q = lane>>4;
  const int m0 = blockIdx.x*64;
  int rg = m0 + lane; if(rg > N_NODESC-1) rg = N_NODESC-1;
  const size_t abyte = (size_t)rg*512;
  f32x4 acc[4][4];
  #pragma unroll
  for(int rt=0;rt<4;rt++)
    #pragma unroll
    for(int ct=0;ct<4;ct++) acc[rt][ct] = (f32x4){0.f,0.f,0.f,0.f};
  f16x8 bf[2][4];
  stage16((const char*)A + abyte + w*16, lds + 0*4096 + w*1024 + lane*16);
  SB;
  stage16((const char*)A + abyte + 64 + w*16, lds + 1*4096 + w*1024 + lane*16);
  SB;
  #pragma unroll
  for(int ct=0;ct<4;ct++){
    int c = w*64 + ct*16 + l15;
    bf[0][ct] = *(const f16x8*)(Bp + ((unsigned)(0*256 + c)*4 + q)*8);
  }
  SB;
  #pragma unroll
  for(int kb=0;kb<8;kb++){
    const int cur = kb&3, rB = kb&1;
    if(kb<6){
      stage16((const char*)A + abyte + (kb+2)*64 + w*16, lds + ((kb+2)&3)*4096 + w*1024 + lane*16);
      SB;
    }
    if(kb<7){
      #pragma unroll
      for(int ct=0;ct<4;ct++){
        int c = w*64 + ct*16 + l15;
        bf[rB^1][ct] = *(const f16x8*)(Bp + ((unsigned)((kb+1)*256 + c)*4 + q)*8);
      }
      SB;
    }
    if(kb<6){ AS_VM(5); } else if(kb==6){ AS_VM(4); } else { AS_VM(0); }
    BAR;
    #pragma unroll
    for(int rt=0;rt<4;rt++){
      f16x8 ah = *(const f16x8*)(lds + cur*4096 + q*1024 + (rt*16+l15)*16);
      #pragma unroll
      for(int ct=0;ct<4;ct++)
        acc[rt][ct] = mfma16(ah, bf[rB][ct], acc[rt][ct]);
    }
  }
  #pragma unroll
  for(int rt=0;rt<4;rt++)
    #pragma unroll
    for(int ct=0;ct<4;ct++){
      int c = w*64 + ct*16 + l15;
      float bv = bias[c];
      #pragma unroll
      for(int j=0;j<4;j++){
        int r = m0 + rt*16 + q*4 + j;
        if(r < N_NODESC) C[(size_t)r*256 + c] = (f16)fmaxf(acc[rt][ct][j] + bv, 0.f);
      }
    }
}

// ---------------- fused GRU v7: 4-buf LDS, distance-2 staging ----------------
// grid 1252 bijective-XCD. Block 64r x 64c, wave = 64r x 16c, acc[6][4].
// LDS: 4 bufs x [plane:2][chunk:4][row:64][16B] = 32KB. Per-iter: 2 stage + 6 B.
// newer-than-B(kb): kb<6 -> S(kb+2)+B(kb+1)=8; kb==6 -> 6; kb==7 -> 0.
__global__ __launch_bounds__(256,2) void k_gru(
    const f16* __restrict__ X, const f16* __restrict__ H, f16* __restrict__ Nh,
    const f16* __restrict__ Wi, const f16* __restrict__ Wh,
    const float* __restrict__ bih, const float* __restrict__ bhh){
  __shared__ f16x8 ldsv[2048];                 // 32KB
  char* lds = (char*)ldsv;
  const int NB = 1252, QQ = NB>>3, RR = NB&7;  // 156, 4
  int bid = blockIdx.x;
  int xcd = bid & 7, jj = bid >> 3;
  int nid = (xcd < RR) ? xcd*(QQ+1) + jj : RR*(QQ+1) + (xcd-RR)*QQ + jj;
  const int m0 = (nid>>2)*64;
  const int cb = nid&3;
  const int tid = threadIdx.x, lane = tid&63, w = tid>>6, l15 = lane&15, q = lane>>4;
  const int cc = cb*64 + w*16 + l15;
  int rg = m0 + lane; if(rg > N_NODESC-1) rg = N_NODESC-1;
  const size_t abyte = (size_t)rg*512;
  const f16* pl[2] = {X, H};
  f32x4 acc[6][4];
  #pragma unroll
  for(int m=0;m<6;m++)
    #pragma unroll
    for(int rt=0;rt<4;rt++) acc[m][rt] = (f32x4){0.f,0.f,0.f,0.f};
  const unsigned wbase = (unsigned)cc*32 + q*8;   // f16 units; +gate*8192 +kb*24576
  f16x8 breg[2][6];
  // prologue: S(0)->buf0, S(1)->buf1, B(0)
  #pragma unroll
  for(int i=0;i<2;i++){
    int pc = w*2 + i; int p = pc>>2, c = pc&3;
    stage16((const char*)pl[p] + abyte + c*16, lds + 0*8192 + p*4096 + c*1024 + lane*16);
  }
  SB;
  #pragma unroll
  for(int i=0;i<2;i++){
    int pc = w*2 + i; int p = pc>>2, c = pc&3;
    stage16((const char*)pl[p] + abyte + 64 + c*16, lds + 1*8192 + p*4096 + c*1024 + lane*16);
  }
  SB;
  {
    breg[0][0] = *(const f16x8*)(Wi + wbase);
    breg[0][1] = *(const f16x8*)(Wi + wbase + 8192);
    breg[0][2] = *(const f16x8*)(Wi + wbase + 16384);
    breg[0][3] = *(const f16x8*)(Wh + wbase);
    breg[0][4] = *(const f16x8*)(Wh + wbase + 8192);
    breg[0][5] = *(const f16x8*)(Wh + wbase + 16384);
  }
  SB;
  #pragma unroll
  for(int kb=0;kb<8;kb++){
    const int cur = kb&3, rB = kb&1;
    if(kb<6){
      #pragma unroll
      for(int i=0;i<2;i++){
        int pc = w*2 + i; int p = pc>>2, c = pc&3;
        stage16((const char*)pl[p] + abyte + (kb+2)*64 + c*16,
                lds + ((kb+2)&3)*8192 + p*4096 + c*1024 + lane*16);
      }
      SB;
    }
    if(kb<7){
      unsigned wo = wbase + (unsigned)(kb+1)*24576u;
      breg[rB^1][0] = *(const f16x8*)(Wi + wo);
      breg[rB^1][1] = *(const f16x8*)(Wi + wo + 8192);
      breg[rB^1][2] = *(const f16x8*)(Wi + wo + 16384);
      breg[rB^1][3] = *(const f16x8*)(Wh + wo);
      breg[rB^1][4] = *(const f16x8*)(Wh + wo + 8192);
      breg[rB^1][5] = *(const f16x8*)(Wh + wo + 16384);
      SB;
    }
    if(kb<6){ AS_VM(8); } else if(kb==6){ AS_VM(6); } else { AS_VM(0); }
    BAR;
    #pragma unroll
    for(int rt=0;rt<4;rt++){
      const int ro = cur*8192 + q*1024 + (rt*16+l15)*16;
      f16x8 ax = *(const f16x8*)(lds + ro);
      f16x8 ah = *(const f16x8*)(lds + 4096 + ro);
      acc[0][rt] = mfma16(ax, breg[rB][0], acc[0][rt]);
      acc[1][rt] = mfma16(ax, breg[rB][1], acc[1][rt]);
      acc[2][rt] = mfma16(ax, breg[rB][2], acc[2][rt]);
      acc[3][rt] = mfma16(ah, breg[rB][3], acc[3][rt]);
      acc[4][rt] = mfma16(ah, breg[rB][4], acc[4][rt]);
      acc[5][rt] = mfma16(ah, breg[rB][5], acc[5][rt]);
    }
  }
  float bir=bih[cc], biz=bih[cc+256], bin=bih[cc+512];
  float bhr=bhh[cc], bhz=bhh[cc+256], bhn=bhh[cc+512];
  #pragma unroll
  for(int rt=0;rt<4;rt++){
    #pragma unroll
    for(int j=0;j<4;j++){
      int r = m0 + rt*16 + q*4 + j;
      if(r < N_NODESC){
        float ir=acc[0][rt][j], iz=acc[1][rt][j], in_=acc[2][rt][j];
        float hr=acc[3][rt][j], hz=acc[4][rt][j], hn=acc[5][rt][j];
        float rgt = sigm(ir+bir + hr+bhr);
        float zg = sigm(iz+biz + hz+bhz);
        float ng = tanh_(in_+bin + rgt*(hn+bhn));
        float ho = (float)H[(size_t)r*256 + cc];
        float v = (1.f-zg)*ng + zg*ho;
        Nh[(size_t)r*256 + cc] = (f16)v;
      }
    }
  }
}

// ---------------- projection: K=256, N=64, 4-buf, distance-2; writes f32 out + f16 feedback ----
__global__ __launch_bounds__(256,2) void k_proj(const f16* __restrict__ A,
    const f16* __restrict__ Bp, const float* __restrict__ bias,
    float* __restrict__ C, f16* __restrict__ Cf16){
  __shared__ f16x8 ldsv[1024];                 // 4 x 4KB
  char* lds = (char*)ldsv;
  const int tid = threadIdx.x, lane = tid&63, w = tid>>6, l15 = lane&15, q = lane>>4;
  const int m0 = blockIdx.x*64;
  const int cc = w*16 + l15;
  int rg = m0 + lane; if(rg > N_NODESC-1) rg = N_NODESC-1;
  const size_t abyte = (size_t)rg*512;
  f32x4 acc[4];
  #pragma unroll
  for(int rt=0;rt<4;rt++) acc[rt] = (f32x4){0.f,0.f,0.f,0.f};
  f16x8 bf[2];
  stage16((const char*)A + abyte + w*16, lds + 0*4096 + w*1024 + lane*16);
  SB;
  stage16((const char*)A + abyte + 64 + w*16, lds + 1*4096 + w*1024 + lane*16);
  SB;
  bf[0] = *(const f16x8*)(Bp + ((unsigned)(0*64 + cc)*4 + q)*8);
  SB;
  #pragma unroll
  for(int kb=0;kb<8;kb++){
    const int cur = kb&3, rB = kb&1;
    if(kb<6){
      stage16((const char*)A + abyte + (kb+2)*64 + w*16, lds + ((kb+2)&3)*4096 + w*1024 + lane*16);
      SB;
    }
    if(kb<7){
      bf[rB^1] = *(const f16x8*)(Bp + ((unsigned)((kb+1)*64 + cc)*4 + q)*8);
      SB;
    }
    if(kb<6){ AS_VM(2); } else if(kb==6){ AS_VM(1); } else { AS_VM(0); }
    BAR;
    #pragma unroll
    for(int rt=0;rt<4;rt++){
      f16x8 ah = *(const f16x8*)(lds + cur*4096 + q*1024 + (rt*16+l15)*16);
      acc[rt] = mfma16(ah, bf[rB], acc[rt]);
    }
  }
  #pragma unroll
  for(int rt=0;rt<4;rt++){
    float bv = bias[cc];
    #pragma unroll
    for(int j=0;j<4;j++){
      int r = m0 + rt*16 + q*4 + j;
      if(r < N_NODESC){
        float v = acc[rt][j] + bv;
        C[(size_t)r*64 + cc] = v;
        Cf16[(size_t)r*64 + cc] = (f16)v;
      }
    }
  }
}

// ---------------- launcher ----------------
extern "C" void kernel_launch(void* const* d_in, const int* in_sizes, int n_in,
                              void* d_out, int out_size, void* d_ws, size_t ws_size,
                              hipStream_t stream){
  const float* x_seq  = (const float*)d_in[0];
  const int*   srcp   = (const int*)  d_in[1];
  const int*   dstp   = (const int*)  d_in[2];
  const float* gcn1_w = (const float*)d_in[3];
  const float* gcn1_b = (const float*)d_in[4];
  const float* gcn2_w = (const float*)d_in[5];
  const float* gcn2_b = (const float*)d_in[6];
  const float* proj_w = (const float*)d_in[7];
  const float* proj_b = (const float*)d_in[8];
  const float* wih[3] = {(const float*)d_in[9],  (const float*)d_in[13], (const float*)d_in[17]};
  const float* whh[3] = {(const float*)d_in[10], (const float*)d_in[14], (const float*)d_in[18]};
  const float* bih[3] = {(const float*)d_in[11], (const float*)d_in[15], (const float*)d_in[19]};
  const float* bhh[3] = {(const float*)d_in[12], (const float*)d_in[16], (const float*)d_in[20]};
  float* out = (float*)d_out;

  const size_t NP = (size_t)N_NODESC*256;
  char* p = (char*)d_ws;
  auto alloc = [&](size_t bytes)->char*{ char* r = p; p += (bytes + 255) & ~(size_t)255; return r; };
  int*   deg_cnt = (int*)  alloc((size_t)2*N_NODESC*4);
  int*   cursor  = deg_cnt + N_NODESC;
  int*   row_ptr = (int*)  alloc((size_t)(N_NODESC+1)*4);
  float* deg_inv = (float*)alloc((size_t)N_NODESC*4);
  float* deg_is  = (float*)alloc((size_t)N_NODESC*4);
  int2*  ev      = (int2*) alloc((size_t)N_EDGESC*8);
  f16* xf16 = (f16*)alloc((size_t)12*N_NODESC*64*2);
  f16* xdec = (f16*)alloc((size_t)N_NODESC*64*2);
  f16* z64  = (f16*)alloc((size_t)N_NODESC*64*2);
  f16* x1   = (f16*)alloc(NP*2);
  f16* xa   = (f16*)alloc(NP*2);
  f16* hbuf = (f16*)alloc((size_t)2*3*NP*2);     // [slot][gru][N*256]
  f16* pk_gcn1 = (f16*)alloc((size_t)64*256*2);
  f16* pk_gcn2 = (f16*)alloc((size_t)256*256*2);
  f16* pk_proj = (f16*)alloc((size_t)256*64*2);
  f16* pk_wi[3]; f16* pk_wh[3];
  for(int i=0;i<3;i++){ pk_wi[i]=(f16*)alloc((size_t)256*768*2); pk_wh[i]=(f16*)alloc((size_t)256*768*2); }

  hipMemsetAsync(deg_cnt, 0, (size_t)2*N_NODESC*4, stream);
  hipMemsetAsync(hbuf,    0, (size_t)3*NP*2, stream);   // slot 0 = h0

  k_hist<<<2500,256,0,stream>>>(dstp, deg_cnt);
  k_scan<<<1,1024,0,stream>>>(deg_cnt, row_ptr, deg_inv, deg_is);
  k_fill<<<2500,256,0,stream>>>(srcp, dstp, row_ptr, cursor, deg_is, ev);
  k_cvt<<<15000,256,0,stream>>>(x_seq, xf16, 12*N_NODESC*64/4);

  k_pack<<<64, 256,0,stream>>>(gcn1_w, pk_gcn1, 64, 256, 0);
  k_pack<<<256,256,0,stream>>>(gcn2_w, pk_gcn2, 256,256, 0);
  k_pack<<<64, 256,0,stream>>>(proj_w, pk_proj, 256, 64, 0);
  for(int i=0;i<3;i++){
    k_pack<<<768,256,0,stream>>>(wih[i], pk_wi[i], 256, 768, 1);
    k_pack<<<768,256,0,stream>>>(whh[i], pk_wh[i], 256, 768, 1);
  }

  auto Hs = [&](int slot, int g)->f16*{ return hbuf + ((size_t)(slot*3+g))*NP; };

  for(int s=0; s<18; s++){
    const f16* xt;
    if(s < 12)       xt = xf16 + (size_t)s*N_NODESC*64;
    else if(s == 12) xt = xf16 + (size_t)11*N_NODESC*64;
    else             xt = xdec;
    int cur = s&1, nxt = cur^1;

    k_agg64 <<<5000,256,0,stream>>>(xt, row_ptr, ev, deg_inv, z64);
    k_gcn1  <<<313, 256,0,stream>>>(z64, pk_gcn1, gcn1_b, x1);
    k_agg256<<<5000,256,0,stream>>>(x1, row_ptr, ev, deg_inv, xa);
    k_gcn2  <<<313, 256,0,stream>>>(xa, pk_gcn2, gcn2_b, xa);

    k_gru<<<1252,256,0,stream>>>(xa,        Hs(cur,0), Hs(nxt,0), pk_wi[0], pk_wh[0], bih[0], bhh[0]);
    k_gru<<<1252,256,0,stream>>>(Hs(nxt,0), Hs(cur,1), Hs(nxt,1), pk_wi[1], pk_wh[1], bih[1], bhh[1]);
    k_gru<<<1252,256,0,stream>>>(Hs(nxt,1), Hs(cur,2), Hs(nxt,2), pk_wi[2], pk_wh[2], bih[2], bhh[2]);

    if(s >= 12)
      k_proj<<<313,256,0,stream>>>(Hs(nxt,2), pk_proj, proj_b, out + (size_t)(s-12)*N_NODESC*64, xdec);
  }
}

// Round 11
// 3787.452 us; speedup vs baseline: 1.6749x; 1.0046x over previous
//
#include <hip/hip_runtime.h>

#define N_NODESC 20000
#define N_EDGESC 640000

typedef _Float16 f16;
typedef __attribute__((ext_vector_type(4))) _Float16 f16x4;
typedef __attribute__((ext_vector_type(8))) _Float16 f16x8;
typedef __attribute__((ext_vector_type(4))) float f32x4;

__device__ __forceinline__ f32x4 mfma16(f16x8 a, f16x8 b, f32x4 c){
  return __builtin_amdgcn_mfma_f32_16x16x32_f16(a, b, c, 0, 0, 0);
}
__device__ __forceinline__ float sigm(float x){ return 1.f/(1.f+__expf(-x)); }
__device__ __forceinline__ float tanh_(float x){
  x = fminf(fmaxf(x, -15.f), 15.f);
  float e = __expf(-2.f*x);
  return (1.f - e)/(1.f + e);
}
__device__ __forceinline__ void stage16(const void* g, void* l){
  __builtin_amdgcn_global_load_lds((const __attribute__((address_space(1))) unsigned int*)g,
                                   (__attribute__((address_space(3))) unsigned int*)l, 16, 0, 0);
}
#define SB       __builtin_amdgcn_sched_barrier(0)
#define AS_VM(n) do{ asm volatile("s_waitcnt vmcnt(" #n ")" ::: "memory"); SB; }while(0)
#define BAR      do{ __builtin_amdgcn_s_barrier(); SB; }while(0)

// ---------------- CSR construction ----------------
__global__ __launch_bounds__(256) void k_hist(const int* __restrict__ dst, int* __restrict__ cnt){
  int e = blockIdx.x*256 + threadIdx.x;
  if(e < N_EDGESC) atomicAdd(&cnt[dst[e]], 1);
}

// pass A: per-block exclusive scan of cnt into row_ptr (local), block totals out
__global__ __launch_bounds__(256) void k_scanA(const int* __restrict__ cnt,
    int* __restrict__ row_ptr, int* __restrict__ btot){
  __shared__ int ws[4];
  int b = blockIdx.x, t = threadIdx.x;
  int i = b*256 + t;
  int v = (i < N_NODESC) ? cnt[i] : 0;
  int lane = t&63, wv = t>>6;
  int incl = v;
  #pragma unroll
  for(int off=1; off<64; off<<=1){ int u = __shfl_up(incl, off); if(lane>=off) incl += u; }
  if(lane==63) ws[wv] = incl;
  __syncthreads();
  int woff = 0;
  for(int k=0;k<wv;k++) woff += ws[k];
  if(i < N_NODESC) row_ptr[i] = woff + incl - v;
  if(t == 255) btot[b] = woff + incl;
}

// pass B: 1 block scans 79 block totals -> exclusive offsets
__global__ __launch_bounds__(128) void k_scanB(const int* __restrict__ btot,
    int* __restrict__ boff, int* __restrict__ row_ptr){
  __shared__ int s[128];
  int t = threadIdx.x;
  int orig = (t < 79) ? btot[t] : 0;
  s[t] = orig;
  __syncthreads();
  #pragma unroll
  for(int off=1; off<128; off<<=1){
    int u = (t>=off) ? s[t-off] : 0;
    __syncthreads();
    s[t] += u;
    __syncthreads();
  }
  if(t < 79) boff[t] = s[t] - orig;
  if(t == 0) row_ptr[N_NODESC] = N_EDGESC;
}

// pass C: apply block offsets + degree normals
__global__ __launch_bounds__(256) void k_scanC(const int* __restrict__ cnt,
    const int* __restrict__ boff, int* __restrict__ row_ptr,
    float* __restrict__ deg_inv, float* __restrict__ deg_is){
  int i = blockIdx.x*256 + threadIdx.x;
  if(i >= N_NODESC) return;
  row_ptr[i] += boff[blockIdx.x];
  float d = (float)(cnt[i] + 1);
  deg_inv[i] = 1.f/d;
  deg_is[i]  = rsqrtf(d);
}

// packed edge record: .x = src index, .y = bitcast(norm)
__global__ __launch_bounds__(256) void k_fill(const int* __restrict__ src, const int* __restrict__ dst,
    const int* __restrict__ row_ptr, int* __restrict__ cursor, const float* __restrict__ deg_is,
    int2* __restrict__ ev){
  int e = blockIdx.x*256 + threadIdx.x;
  if(e >= N_EDGESC) return;
  int d = dst[e], s = src[e];
  int p = atomicAdd(&cursor[d], 1);
  int2 v;
  v.x = s;
  v.y = __float_as_int(deg_is[s]*deg_is[d]);
  ev[row_ptr[d] + p] = v;
}

// ---------------- x_seq f32 -> f16 conversion (once) ----------------
__global__ __launch_bounds__(256) void k_cvt(const float* __restrict__ x, f16* __restrict__ o, int n4){
  int i = blockIdx.x*256 + threadIdx.x;
  if(i >= n4) return;
  f32x4 v = *(const f32x4*)(x + (size_t)i*4);
  *(f16x4*)(o + (size_t)i*4) = __builtin_convertvector(v, f16x4);
}

// ---------------- weight packing (f16, MFMA B-fragment order) ----------------
__global__ __launch_bounds__(256) void k_pack(const float* __restrict__ w, f16* __restrict__ dstp,
    int K, int NO, int trans){
  int t = blockIdx.x*256 + threadIdx.x;
  if(t >= K*NO) return;
  int i = t&7, g = (t>>3)&3, rest = t>>5;
  int c = rest % NO, kb = rest / NO;
  int k = kb*32 + g*8 + i;
  float v = trans ? w[(size_t)c*K + k] : w[(size_t)k*NO + c];
  dstp[t] = (f16)v;
}

// ---------------- aggregation ----------------
__global__ __launch_bounds__(256) void k_agg64(const f16* __restrict__ x,
    const int* __restrict__ row_ptr, const int2* __restrict__ ev,
    const float* __restrict__ deg_inv, f16* __restrict__ O){
  int n = (blockIdx.x*256 + threadIdx.x)>>6;
  int c = threadIdx.x&63;
  if(n >= N_NODESC) return;
  float acc = deg_inv[n]*(float)x[(size_t)n*64 + c];
  int e0 = row_ptr[n], e1 = row_ptr[n+1];
  int e = e0;
  for(; e+4<=e1; e+=4){
    int2 a=ev[e], b=ev[e+1], cc=ev[e+2], d=ev[e+3];
    float v0=(float)x[(size_t)a.x*64+c],  v1=(float)x[(size_t)b.x*64+c];
    float v2=(float)x[(size_t)cc.x*64+c], v3=(float)x[(size_t)d.x*64+c];
    acc += __int_as_float(a.y)*v0 + __int_as_float(b.y)*v1
         + __int_as_float(cc.y)*v2 + __int_as_float(d.y)*v3;
  }
  for(; e<e1; e++){ int2 a=ev[e]; acc += __int_as_float(a.y)*(float)x[(size_t)a.x*64+c]; }
  O[(size_t)n*64+c] = (f16)acc;
}

__global__ __launch_bounds__(256) void k_agg256(const f16* __restrict__ x1,
    const int* __restrict__ row_ptr, const int2* __restrict__ ev,
    const float* __restrict__ deg_inv, f16* __restrict__ O){
  int n = (blockIdx.x*256 + threadIdx.x)>>6;
  int lane = threadIdx.x&63;
  if(n >= N_NODESC) return;
  const f16x4* xv = (const f16x4*)x1;
  f32x4 acc = __builtin_convertvector(xv[(size_t)n*64 + lane], f32x4) * deg_inv[n];
  int e0 = row_ptr[n], e1 = row_ptr[n+1];
  int e = e0;
  for(; e+4<=e1; e+=4){
    int2 a=ev[e], b=ev[e+1], cc=ev[e+2], d=ev[e+3];
    f32x4 v0=__builtin_convertvector(xv[(size_t)a.x*64+lane],  f32x4);
    f32x4 v1=__builtin_convertvector(xv[(size_t)b.x*64+lane],  f32x4);
    f32x4 v2=__builtin_convertvector(xv[(size_t)cc.x*64+lane], f32x4);
    f32x4 v3=__builtin_convertvector(xv[(size_t)d.x*64+lane],  f32x4);
    acc += v0*__int_as_float(a.y); acc += v1*__int_as_float(b.y);
    acc += v2*__int_as_float(cc.y); acc += v3*__int_as_float(d.y);
  }
  for(; e<e1; e++){ int2 a=ev[e];
    acc += __builtin_convertvector(xv[(size_t)a.x*64+lane], f32x4)*__int_as_float(a.y); }
  ((f16x4*)O)[(size_t)n*64+lane] = __builtin_convertvector(acc, f16x4);
}

// ---------------- GCN1: K=64, N=256, single-stage LDS ----------------
__global__ __launch_bounds__(256) void k_gcn1(const f16* __restrict__ A,
    const f16* __restrict__ Bp, const float* __restrict__ bias, f16* __restrict__ C){
  __shared__ f16x8 ldsv[512];                  // [kb:2][q:4][row:64][16B] = 8KB
  char* lds = (char*)ldsv;
  const int tid = threadIdx.x, lane = tid&63, w = tid>>6, l15 = lane&15, q = lane>>4;
  const int m0 = blockIdx.x*64;
  int rg = m0 + lane; if(rg > N_NODESC-1) rg = N_NODESC-1;
  #pragma unroll
  for(int i=0;i<2;i++){
    int region = i*4 + w;
    int kbb = region>>2, qq = region&3;
    stage16((const char*)A + (size_t)rg*128 + kbb*64 + qq*16, lds + region*1024 + lane*16);
  }
  AS_VM(0);
  BAR;
  f32x4 acc[4][4];
  #pragma unroll
  for(int rt=0;rt<4;rt++)
    #pragma unroll
    for(int ct=0;ct<4;ct++) acc[rt][ct] = (f32x4){0.f,0.f,0.f,0.f};
  #pragma unroll
  for(int kb=0;kb<2;kb++){
    f16x8 bf[4];
    #pragma unroll
    for(int ct=0;ct<4;ct++){
      int c = w*64 + ct*16 + l15;
      bf[ct] = *(const f16x8*)(Bp + ((unsigned)(kb*256 + c)*4 + q)*8);
    }
    #pragma unroll
    for(int rt=0;rt<4;rt++){
      f16x8 ah = *(const f16x8*)(lds + (kb*4+q)*1024 + (rt*16+l15)*16);
      #pragma unroll
      for(int ct=0;ct<4;ct++)
        acc[rt][ct] = mfma16(ah, bf[ct], acc[rt][ct]);
    }
  }
  #pragma unroll
  for(int rt=0;rt<4;rt++)
    #pragma unroll
    for(int ct=0;ct<4;ct++){
      int c = w*64 + ct*16 + l15;
      float bv = bias[c];
      #pragma unroll
      for(int j=0;j<4;j++){
        int r = m0 + rt*16 + q*4 + j;
        if(r < N_NODESC) C[(size_t)r*256 + c] = (f16)fmaxf(acc[rt][ct][j] + bv, 0.f);
      }
    }
}

// ---------------- GCN2: A-tile fully resident in LDS (32KB), barrier-free K-loop ----------
__global__ __launch_bounds__(256,3) void k_gcn2(const f16* __restrict__ A,
    const f16* __restrict__ Bp, const float* __restrict__ bias, f16* __restrict__ C){
  __shared__ f16x8 ldsv[2048];                 // 32KB: [kb:8][q:4][row:64][16B]
  char* lds = (char*)ldsv;
  const int tid = threadIdx.x, lane = tid&63, w = tid>>6, l15 = lane&15, q = lane>>4;
  const int m0 = blockIdx.x*64;
  int rg = m0 + lane; if(rg > N_NODESC-1) rg = N_NODESC-1;
  const size_t abyte = (size_t)rg*512;
  // stage whole tile: wave w stages q-chunk w of every kb
  #pragma unroll
  for(int kb=0;kb<8;kb++)
    stage16((const char*)A + abyte + kb*64 + w*16, lds + kb*4096 + w*1024 + lane*16);
  AS_VM(0);
  BAR;
  f32x4 acc[4][4];
  #pragma unroll
  for(int rt=0;rt<4;rt++)
    #pragma unroll
    for(int ct=0;ct<4;ct++) acc[rt][ct] = (f32x4){0.f,0.f,0.f,0.f};
  f16x8 bf[2][4];
  #pragma unroll
  for(int ct=0;ct<4;ct++){
    int c = w*64 + ct*16 + l15;
    bf[0][ct] = *(const f16x8*)(Bp + ((unsigned)(0*256 + c)*4 + q)*8);
  }
  #pragma unroll
  for(int kb=0;kb<8;kb++){
    const int rB = kb&1;
    if(kb<7){
      #pragma unroll
      for(int ct=0;ct<4;ct++){
        int c = w*64 + ct*16 + l15;
        bf[rB^1][ct] = *(const f16x8*)(Bp + ((unsigned)((kb+1)*256 + c)*4 + q)*8);
      }
    }
    #pragma unroll
    for(int rt=0;rt<4;rt++){
      f16x8 ah = *(const f16x8*)(lds + kb*4096 + q*1024 + (rt*16+l15)*16);
      #pragma unroll
      for(int ct=0;ct<4;ct++)
        acc[rt][ct] = mfma16(ah, bf[rB][ct], acc[rt][ct]);
    }
  }
  #pragma unroll
  for(int rt=0;rt<4;rt++)
    #pragma unroll
    for(int ct=0;ct<4;ct++){
      int c = w*64 + ct*16 + l15;
      float bv = bias[c];
      #pragma unroll
      for(int j=0;j<4;j++){
        int r = m0 + rt*16 + q*4 + j;
        if(r < N_NODESC) C[(size_t)r*256 + c] = (f16)fmaxf(acc[rt][ct][j] + bv, 0.f);
      }
    }
}

// ---------------- fused GRU v8: X+H tiles fully resident (64KB), barrier-free K-loop ------
// grid 1252 bijective-XCD. Block 64r x 64c, wave = 64r x 16c, acc[6][4].
// LDS [p:2][kb:8][q:4][row:64][16B] = 64KB. 16 stage16/thread, ONE vmcnt(0)+barrier total.
__global__ __launch_bounds__(256,2) void k_gru(
    const f16* __restrict__ X, const f16* __restrict__ H, f16* __restrict__ Nh,
    const f16* __restrict__ Wi, const f16* __restrict__ Wh,
    const float* __restrict__ bih, const float* __restrict__ bhh){
  __shared__ f16x8 ldsv[4096];                 // 64KB
  char* lds = (char*)ldsv;
  const int NB = 1252, QQ = NB>>3, RR = NB&7;  // 156, 4
  int bid = blockIdx.x;
  int xcd = bid & 7, jj = bid >> 3;
  int nid = (xcd < RR) ? xcd*(QQ+1) + jj : RR*(QQ+1) + (xcd-RR)*QQ + jj;
  const int m0 = (nid>>2)*64;
  const int cb = nid&3;
  const int tid = threadIdx.x, lane = tid&63, w = tid>>6, l15 = lane&15, q = lane>>4;
  const int cc = cb*64 + w*16 + l15;
  int rg = m0 + lane; if(rg > N_NODESC-1) rg = N_NODESC-1;
  const size_t abyte = (size_t)rg*512;
  const f16* pl[2] = {X, H};
  // stage whole X and H tiles: wave w takes q-chunk w of all 16 (p,kb) regions
  #pragma unroll
  for(int p=0;p<2;p++)
    #pragma unroll
    for(int kb=0;kb<8;kb++)
      stage16((const char*)pl[p] + abyte + kb*64 + w*16,
              lds + p*32768 + kb*4096 + w*1024 + lane*16);
  AS_VM(0);
  BAR;
  f32x4 acc[6][4];
  #pragma unroll
  for(int m=0;m<6;m++)
    #pragma unroll
    for(int rt=0;rt<4;rt++) acc[m][rt] = (f32x4){0.f,0.f,0.f,0.f};
  const unsigned wbase = (unsigned)cc*32 + q*8;   // f16 units; +gate*8192 +kb*24576
  f16x8 breg[2][6];
  {
    breg[0][0] = *(const f16x8*)(Wi + wbase);
    breg[0][1] = *(const f16x8*)(Wi + wbase + 8192);
    breg[0][2] = *(const f16x8*)(Wi + wbase + 16384);
    breg[0][3] = *(const f16x8*)(Wh + wbase);
    breg[0][4] = *(const f16x8*)(Wh + wbase + 8192);
    breg[0][5] = *(const f16x8*)(Wh + wbase + 16384);
  }
  #pragma unroll
  for(int kb=0;kb<8;kb++){
    const int rB = kb&1;
    if(kb<7){
      unsigned wo = wbase + (unsigned)(kb+1)*24576u;
      breg[rB^1][0] = *(const f16x8*)(Wi + wo);
      breg[rB^1][1] = *(const f16x8*)(Wi + wo + 8192);
      breg[rB^1][2] = *(const f16x8*)(Wi + wo + 16384);
      breg[rB^1][3] = *(const f16x8*)(Wh + wo);
      breg[rB^1][4] = *(const f16x8*)(Wh + wo + 8192);
      breg[rB^1][5] = *(const f16x8*)(Wh + wo + 16384);
    }
    #pragma unroll
    for(int rt=0;rt<4;rt++){
      const int ro = kb*4096 + q*1024 + (rt*16+l15)*16;
      f16x8 ax = *(const f16x8*)(lds + ro);
      f16x8 ah = *(const f16x8*)(lds + 32768 + ro);
      acc[0][rt] = mfma16(ax, breg[rB][0], acc[0][rt]);
      acc[1][rt] = mfma16(ax, breg[rB][1], acc[1][rt]);
      acc[2][rt] = mfma16(ax, breg[rB][2], acc[2][rt]);
      acc[3][rt] = mfma16(ah, breg[rB][3], acc[3][rt]);
      acc[4][rt] = mfma16(ah, breg[rB][4], acc[4][rt]);
      acc[5][rt] = mfma16(ah, breg[rB][5], acc[5][rt]);
    }
  }
  float bir=bih[cc], biz=bih[cc+256], bin=bih[cc+512];
  float bhr=bhh[cc], bhz=bhh[cc+256], bhn=bhh[cc+512];
  #pragma unroll
  for(int rt=0;rt<4;rt++){
    #pragma unroll
    for(int j=0;j<4;j++){
      int r = m0 + rt*16 + q*4 + j;
      if(r < N_NODESC){
        float ir=acc[0][rt][j], iz=acc[1][rt][j], in_=acc[2][rt][j];
        float hr=acc[3][rt][j], hz=acc[4][rt][j], hn=acc[5][rt][j];
        float rgt = sigm(ir+bir + hr+bhr);
        float zg = sigm(iz+biz + hz+bhz);
        float ng = tanh_(in_+bin + rgt*(hn+bhn));
        float ho = (float)H[(size_t)r*256 + cc];
        float v = (1.f-zg)*ng + zg*ho;
        Nh[(size_t)r*256 + cc] = (f16)v;
      }
    }
  }
}

// ---------------- projection: A resident (32KB), barrier-free; f32 out + f16 feedback ----
__global__ __launch_bounds__(256,4) void k_proj(const f16* __restrict__ A,
    const f16* __restrict__ Bp, const float* __restrict__ bias,
    float* __restrict__ C, f16* __restrict__ Cf16){
  __shared__ f16x8 ldsv[2048];                 // 32KB
  char* lds = (char*)ldsv;
  const int tid = threadIdx.x, lane = tid&63, w = tid>>6, l15 = lane&15, q = lane>>4;
  const int m0 = blockIdx.x*64;
  const int cc = w*16 + l15;
  int rg = m0 + lane; if(rg > N_NODESC-1) rg = N_NODESC-1;
  const size_t abyte = (size_t)rg*512;
  #pragma unroll
  for(int kb=0;kb<8;kb++)
    stage16((const char*)A + abyte + kb*64 + w*16, lds + kb*4096 + w*1024 + lane*16);
  AS_VM(0);
  BAR;
  f32x4 acc[4];
  #pragma unroll
  for(int rt=0;rt<4;rt++) acc[rt] = (f32x4){0.f,0.f,0.f,0.f};
  f16x8 bf[2];
  bf[0] = *(const f16x8*)(Bp + ((unsigned)(0*64 + cc)*4 + q)*8);
  #pragma unroll
  for(int kb=0;kb<8;kb++){
    const int rB = kb&1;
    if(kb<7)
      bf[rB^1] = *(const f16x8*)(Bp + ((unsigned)((kb+1)*64 + cc)*4 + q)*8);
    #pragma unroll
    for(int rt=0;rt<4;rt++){
      f16x8 ah = *(const f16x8*)(lds + kb*4096 + q*1024 + (rt*16+l15)*16);
      acc[rt] = mfma16(ah, bf[rB], acc[rt]);
    }
  }
  #pragma unroll
  for(int rt=0;rt<4;rt++){
    float bv = bias[cc];
    #pragma unroll
    for(int j=0;j<4;j++){
      int r = m0 + rt*16 + q*4 + j;
      if(r < N_NODESC){
        float v = acc[rt][j] + bv;
        C[(size_t)r*64 + cc] = v;
        Cf16[(size_t)r*64 + cc] = (f16)v;
      }
    }
  }
}

// ---------------- launcher ----------------
extern "C" void kernel_launch(void* const* d_in, const int* in_sizes, int n_in,
                              void* d_out, int out_size, void* d_ws, size_t ws_size,
                              hipStream_t stream){
  const float* x_seq  = (const float*)d_in[0];
  const int*   srcp   = (const int*)  d_in[1];
  const int*   dstp   = (const int*)  d_in[2];
  const float* gcn1_w = (const float*)d_in[3];
  const float* gcn1_b = (const float*)d_in[4];
  const float* gcn2_w = (const float*)d_in[5];
  const float* gcn2_b = (const float*)d_in[6];
  const float* proj_w = (const float*)d_in[7];
  const float* proj_b = (const float*)d_in[8];
  const float* wih[3] = {(const float*)d_in[9],  (const float*)d_in[13], (const float*)d_in[17]};
  const float* whh[3] = {(const float*)d_in[10], (const float*)d_in[14], (const float*)d_in[18]};
  const float* bih[3] = {(const float*)d_in[11], (const float*)d_in[15], (const float*)d_in[19]};
  const float* bhh[3] = {(const float*)d_in[12], (const float*)d_in[16], (const float*)d_in[20]};
  float* out = (float*)d_out;

  const size_t NP = (size_t)N_NODESC*256;
  char* p = (char*)d_ws;
  auto alloc = [&](size_t bytes)->char*{ char* r = p; p += (bytes + 255) & ~(size_t)255; return r; };
  int*   deg_cnt = (int*)  alloc((size_t)2*N_NODESC*4);
  int*   cursor  = deg_cnt + N_NODESC;
  int*   row_ptr = (int*)  alloc((size_t)(N_NODESC+1)*4);
  float* deg_inv = (float*)alloc((size_t)N_NODESC*4);
  float* deg_is  = (float*)alloc((size_t)N_NODESC*4);
  int*   btot    = (int*)  alloc((size_t)128*4);
  int*   boff    = (int*)  alloc((size_t)128*4);
  int2*  ev      = (int2*) alloc((size_t)N_EDGESC*8);
  f16* xf16 = (f16*)alloc((size_t)12*N_NODESC*64*2);
  f16* xdec = (f16*)alloc((size_t)N_NODESC*64*2);
  f16* z64  = (f16*)alloc((size_t)N_NODESC*64*2);
  f16* x1   = (f16*)alloc(NP*2);
  f16* xa   = (f16*)alloc(NP*2);
  f16* hbuf = (f16*)alloc((size_t)2*3*NP*2);     // [slot][gru][N*256]
  f16* pk_gcn1 = (f16*)alloc((size_t)64*256*2);
  f16* pk_gcn2 = (f16*)alloc((size_t)256*256*2);
  f16* pk_proj = (f16*)alloc((size_t)256*64*2);
  f16* pk_wi[3]; f16* pk_wh[3];
  for(int i=0;i<3;i++){ pk_wi[i]=(f16*)alloc((size_t)256*768*2); pk_wh[i]=(f16*)alloc((size_t)256*768*2); }

  hipMemsetAsync(deg_cnt, 0, (size_t)2*N_NODESC*4, stream);
  hipMemsetAsync(hbuf,    0, (size_t)3*NP*2, stream);   // slot 0 = h0

  k_hist <<<2500,256,0,stream>>>(dstp, deg_cnt);
  k_scanA<<<79,  256,0,stream>>>(deg_cnt, row_ptr, btot);
  k_scanB<<<1,   128,0,stream>>>(btot, boff, row_ptr);
  k_scanC<<<79,  256,0,stream>>>(deg_cnt, boff, row_ptr, deg_inv, deg_is);
  k_fill <<<2500,256,0,stream>>>(srcp, dstp, row_ptr, cursor, deg_is, ev);
  k_cvt  <<<15000,256,0,stream>>>(x_seq, xf16, 12*N_NODESC*64/4);

  k_pack<<<64, 256,0,stream>>>(gcn1_w, pk_gcn1, 64, 256, 0);
  k_pack<<<256,256,0,stream>>>(gcn2_w, pk_gcn2, 256,256, 0);
  k_pack<<<64, 256,0,stream>>>(proj_w, pk_proj, 256, 64, 0);
  for(int i=0;i<3;i++){
    k_pack<<<768,256,0,stream>>>(wih[i], pk_wi[i], 256, 768, 1);
    k_pack<<<768,256,0,stream>>>(whh[i], pk_wh[i], 256, 768, 1);
  }

  auto Hs = [&](int slot, int g)->f16*{ return hbuf + ((size_t)(slot*3+g))*NP; };

  for(int s=0; s<18; s++){
    const f16* xt;
    if(s < 12)       xt = xf16 + (size_t)s*N_NODESC*64;
    else if(s == 12) xt = xf16 + (size_t)11*N_NODESC*64;
    else             xt = xdec;
    int cur = s&1, nxt = cur^1;

    k_agg64 <<<5000,256,0,stream>>>(xt, row_ptr, ev, deg_inv, z64);
    k_gcn1  <<<313, 256,0,stream>>>(z64, pk_gcn1, gcn1_b, x1);
    k_agg256<<<5000,256,0,stream>>>(x1, row_ptr, ev, deg_inv, xa);
    k_gcn2  <<<313, 256,0,stream>>>(xa, pk_gcn2, gcn2_b, xa);

    k_gru<<<1252,256,0,stream>>>(xa,        Hs(cur,0), Hs(nxt,0), pk_wi[0], pk_wh[0], bih[0], bhh[0]);
    k_gru<<<1252,256,0,stream>>>(Hs(nxt,0), Hs(cur,1), Hs(nxt,1), pk_wi[1], pk_wh[1], bih[1], bhh[1]);
    k_gru<<<1252,256,0,stream>>>(Hs(nxt,1), Hs(cur,2), Hs(nxt,2), pk_wi[2], pk_wh[2], bih[2], bhh[2]);

    if(s >= 12)
      k_proj<<<313,256,0,stream>>>(Hs(nxt,2), pk_proj, proj_b, out + (size_t)(s-12)*N_NODESC*64, xdec);
  }
}